// Round 12
// baseline (285.082 us; speedup 1.0000x reference)
//
#include <hip/hip_runtime.h>
#include <hip/hip_bf16.h>
#include <cstdint>
#include <cstddef>

typedef __bf16 bf16;
typedef __bf16 bf16x4 __attribute__((ext_vector_type(4)));
typedef __bf16 bf16x8 __attribute__((ext_vector_type(8)));
typedef float f32x4 __attribute__((ext_vector_type(4)));

#define D_MODEL 2048
#define SEQ     2048
#define NH      16
#define HD      128
#define BATCH   2
#define QKV_LD  6144

#define SBAR()  __builtin_amdgcn_sched_barrier(0)
#define HWBAR() do { SBAR(); __builtin_amdgcn_s_barrier(); SBAR(); } while (0)

// ---------------- async global->LDS 16B ----------------
__device__ __forceinline__ void gld16(void* lds, const void* g) {
    __builtin_amdgcn_global_load_lds(
        (const __attribute__((address_space(1))) unsigned int*)g,
        (__attribute__((address_space(3))) unsigned int*)lds,
        16, 0, 0);
}

// ---------------- fused fp32 -> bf16 convert (x, Wq, Wk, Wv, Wo) ----------------
__global__ __launch_bounds__(256) void cvt_all(const float* __restrict__ x,
                                               const float* __restrict__ Wq,
                                               const float* __restrict__ Wk,
                                               const float* __restrict__ Wv,
                                               const float* __restrict__ Wo,
                                               bf16* __restrict__ out) {
    int i = (blockIdx.x * 256 + threadIdx.x) * 4;  // 25165824 total elems
    const float* src;
    int off;
    if (i < 8388608) { src = x; off = i; }
    else {
        int j = i - 8388608;
        int seg = j >> 22;
        src = (seg == 0) ? Wq : (seg == 1) ? Wk : (seg == 2) ? Wv : Wo;
        off = j & 4194303;
    }
    float4 v = *(const float4*)(src + off);
    bf16* o = out + i;
    o[0] = (bf16)v.x; o[1] = (bf16)v.y; o[2] = (bf16)v.z; o[3] = (bf16)v.w;
}

// ---------------- RoPE tables (cos/sin, S x 64) ----------------
__global__ __launch_bounds__(256) void rope_tables_k(float* __restrict__ cosd,
                                                     float* __restrict__ sind) {
    int id = blockIdx.x * 256 + threadIdx.x;  // SEQ*64
    int s = id >> 6, d = id & 63;
    float freq = powf(10000.f, -(float)d * (1.f / 64.f));
    float a = (float)s * freq;
    float sn, c;
    sincosf(a, &sn, &c);
    cosd[id] = c;
    sind[id] = sn;
}

// ---------------- RoPE apply (in-place, row stride ld) ----------------
__global__ __launch_bounds__(256) void rope_apply(bf16* __restrict__ T,
                                                  const float* __restrict__ cosd,
                                                  const float* __restrict__ sind,
                                                  float scale, int ld) {
    int id = blockIdx.x * 256 + threadIdx.x;   // B*S*NH*64
    int row = id >> 10;                        // B*S
    int p = id & 1023;
    int h = p >> 6, d = p & 63;
    int s = row & (SEQ - 1);
    size_t base = (size_t)row * ld + h * HD + d;
    float x1 = (float)T[base];
    float x2 = (float)T[base + 64];
    float c = cosd[(s << 6) + d];
    float sn = sind[(s << 6) + d];
    T[base]      = (bf16)((x1 * c - x2 * sn) * scale);
    T[base + 64] = (bf16)((x2 * c + x1 * sn) * scale);
}

// ---------------- V transpose: [B,S,(ld)] head cols -> [B,H,D,S] ----------------
__global__ __launch_bounds__(256) void transpose_v(const bf16* __restrict__ V,
                                                   bf16* __restrict__ Vt, int ld) {
    __shared__ bf16 t[32][33];
    int s0 = blockIdx.x * 32;
    int d0 = blockIdx.y * 32;
    int bh = blockIdx.z;
    int b = bh >> 4, h = bh & 15;
    int tx = threadIdx.x & 31, ty = threadIdx.x >> 5;  // ty 0..7
#pragma unroll
    for (int i = 0; i < 32; i += 8)
        t[ty + i][tx] = V[((size_t)(b * SEQ + s0 + ty + i)) * ld + h * HD + d0 + tx];
    __syncthreads();
#pragma unroll
    for (int i = 0; i < 32; i += 8)
        Vt[((size_t)bh * HD + d0 + ty + i) * SEQ + s0 + tx] = t[tx][ty + i];
}

// ---------------- 128x256 NT GEMM, deep pipeline (2 tiles ahead) ----------------
// 512 thr = 8 waves (2m x 4n), BK=64. A double-buffered (staged ph1, t+2),
// B triple-buffered (staged ph0, t+2). Boundary wait vmcnt(6): tile t+2's six
// loads stay in flight across all of tile t+1 (~4 phases) -> HBM latency hidden.
template <int OUTF32>
__global__ __launch_bounds__(512, 2)
void gemm128(const bf16* __restrict__ A, const bf16* __restrict__ B,
             void* __restrict__ Cout, int M, int N, int K) {
    __shared__ __align__(16) bf16 ldsA[2][128 * 64];      // 32 KB
    __shared__ __align__(16) bf16 ldsB[3][2][128 * 64];   // 96 KB

    const int nN = N >> 8;
    const int cpx = gridDim.x >> 3;
    const int lin = (blockIdx.x & 7) * cpx + (blockIdx.x >> 3);  // XCD-chunked
    const int m0 = (lin / nN) * 128, n0 = (lin % nN) * 256;

    const int tid = threadIdx.x;
    const int w = tid >> 6, l = tid & 63;
    const int wm = w >> 2, wn = w & 3;
    const int lg = l >> 4, lc = l & 15;
    const int swz = (lc & 7) << 4;
    const int NT = K >> 6;

    f32x4 acc[2][4][2] = {};   // [nq][mt][nt]

    auto stageA = [&](int tau) {
        bf16* dst = &ldsA[tau & 1][0];
#pragma unroll
        for (int j = 0; j < 2; ++j) {
            int r = w * 16 + j * 8 + (l >> 3);
            int scb = ((l & 7) * 16) ^ ((r & 7) << 4);
            gld16(dst + (w * 16 + j * 8) * 64, A + (size_t)(m0 + r) * K + tau * 64 + (scb >> 1));
        }
    };
    auto stageB = [&](int tau, int u) {
        bf16* dst = &ldsB[tau % 3][u][0];
#pragma unroll
        for (int j = 0; j < 2; ++j) {
            int r = w * 16 + j * 8 + (l >> 3);
            int scb = ((l & 7) * 16) ^ ((r & 7) << 4);
            gld16(dst + (w * 16 + j * 8) * 64, B + (size_t)(n0 + u * 128 + r) * K + tau * 64 + (scb >> 1));
        }
    };

    // prologue: tiles 0 and 1 fully staged (12 loads); wait tile0 (6 left)
    stageA(0); stageB(0, 0); stageB(0, 1);
    stageA(1); stageB(1, 0); stageB(1, 1);
    SBAR();
    asm volatile("s_waitcnt vmcnt(6)" ::: "memory");
    HWBAR();

    for (int t = 0; t < NT; ++t) {
        const char* Ab = (const char*)&ldsA[t & 1][0];
        const char* Bb = (const char*)&ldsB[t % 3][wn >> 1][0];
        const int brow0 = (wn & 1) * 64;
        bf16x8 Af[4][2], Bf[2][2];

        // ---- phase 0 (nq0): read A + B(nq0); stage B0,B1(t+2) ----
#pragma unroll
        for (int mt = 0; mt < 4; ++mt)
#pragma unroll
            for (int ks = 0; ks < 2; ++ks)
                Af[mt][ks] = *(const bf16x8*)(Ab + (wm * 64 + mt * 16 + lc) * 128 + ((ks * 64 + lg * 16) ^ swz));
#pragma unroll
        for (int nt = 0; nt < 2; ++nt)
#pragma unroll
            for (int ks = 0; ks < 2; ++ks)
                Bf[nt][ks] = *(const bf16x8*)(Bb + (brow0 + nt * 16 + lc) * 128 + ((ks * 64 + lg * 16) ^ swz));
        if (t + 2 < NT) { stageB(t + 2, 0); stageB(t + 2, 1); }
        HWBAR();
        __builtin_amdgcn_s_setprio(1);
#pragma unroll
        for (int mt = 0; mt < 4; ++mt)
#pragma unroll
            for (int nt = 0; nt < 2; ++nt)
#pragma unroll
                for (int ks = 0; ks < 2; ++ks)
                    acc[0][mt][nt] = __builtin_amdgcn_mfma_f32_16x16x32_bf16(Af[mt][ks], Bf[nt][ks], acc[0][mt][nt], 0, 0, 0);
        __builtin_amdgcn_s_setprio(0);
        HWBAR();

        // ---- phase 1 (nq1): read B(nq1); stage A(t+2) (A(t) reads done) ----
#pragma unroll
        for (int nt = 0; nt < 2; ++nt)
#pragma unroll
            for (int ks = 0; ks < 2; ++ks)
                Bf[nt][ks] = *(const bf16x8*)(Bb + (brow0 + 32 + nt * 16 + lc) * 128 + ((ks * 64 + lg * 16) ^ swz));
        if (t + 2 < NT) stageA(t + 2);
        HWBAR();
        __builtin_amdgcn_s_setprio(1);
#pragma unroll
        for (int mt = 0; mt < 4; ++mt)
#pragma unroll
            for (int nt = 0; nt < 2; ++nt)
#pragma unroll
                for (int ks = 0; ks < 2; ++ks)
                    acc[1][mt][nt] = __builtin_amdgcn_mfma_f32_16x16x32_bf16(Af[mt][ks], Bf[nt][ks], acc[1][mt][nt], 0, 0, 0);
        __builtin_amdgcn_s_setprio(0);
        SBAR();
        // need tile t+1 resident; tile t+2's 6 loads (if issued) stay in flight
        if (t + 2 < NT) asm volatile("s_waitcnt vmcnt(6)" ::: "memory");
        else            asm volatile("s_waitcnt vmcnt(0)" ::: "memory");
        HWBAR();
    }

    // ---- epilogue ----
#pragma unroll
    for (int nq = 0; nq < 2; ++nq)
#pragma unroll
        for (int mt = 0; mt < 4; ++mt)
#pragma unroll
            for (int nt = 0; nt < 2; ++nt)
#pragma unroll
                for (int rr = 0; rr < 4; ++rr) {
                    size_t row = (size_t)m0 + wm * 64 + mt * 16 + lg * 4 + rr;
                    size_t col = (size_t)n0 + wn * 64 + nq * 32 + nt * 16 + lc;
                    float v = acc[nq][mt][nt][rr];
                    if (OUTF32) ((float*)Cout)[row * N + col] = v;
                    else        ((bf16*)Cout)[row * N + col] = (bf16)v;
                }
}

// ---------------- Flash attention (unchanged from R5/R8) ----------------
__global__ __launch_bounds__(256)
void flash_attn(const bf16* __restrict__ QKV, const bf16* __restrict__ Vt,
                bf16* __restrict__ O) {
    __shared__ __align__(16) bf16 Ks[2][64 * 128];   // [key][d], rows 256B
    __shared__ __align__(16) bf16 Vs[2][128 * 64];   // [d][key], rows 128B
    __shared__ __align__(16) bf16 p_lds[4][16 * 64]; // per-wave P[q][key], rows 128B

    const int bid = blockIdx.x;                   // 512
    const int lin = (bid & 7) * 64 + (bid >> 3);  // XCD-chunked
    const int bh = lin >> 4;
    const int jj = lin & 15;
    const int b = bh >> 4, h = bh & 15;

    const int tid = threadIdx.x;
    const int w = tid >> 6, l = tid & 63;
    const int lg = l >> 4, lc = l & 15;
    const int kswz = (lc & 7) << 4;
    char* pb = (char*)&p_lds[w][0];

    auto stageK = [&](int p, int kb) {
#pragma unroll
        for (int c = 0; c < 4; ++c) {
            int r = c * 16 + w * 4 + (l >> 4);
            int scb = ((l & 15) * 16) ^ ((r & 7) << 4);
            const bf16* g = QKV + ((size_t)(b * SEQ + kb * 64 + r)) * QKV_LD + D_MODEL + h * HD + (scb >> 1);
            gld16(&Ks[p][(c * 16 + w * 4) * 128], g);
        }
    };
    auto stageV = [&](int p, int kb) {
#pragma unroll
        for (int c = 0; c < 4; ++c) {
            int r = c * 32 + w * 8 + (l >> 3);
            int scb = ((l & 7) * 16) ^ ((r & 7) << 4);
            const bf16* g = Vt + ((size_t)bh * HD + r) * SEQ + kb * 64 + (scb >> 1);
            gld16(&Vs[p][(c * 32 + w * 8) * 64], g);
        }
    };

    int cur = 0;
#pragma unroll 1
    for (int ti = 0; ti < 2; ++ti) {
        const int qt = ti ? jj : (31 - jj);       // long tile first
        const int q0 = qt * 64 + w * 16;

        const bf16* qp = QKV + ((size_t)(b * SEQ + q0 + lc)) * QKV_LD + h * HD + lg * 8;
        bf16x8 qf[4];
#pragma unroll
        for (int kc = 0; kc < 4; ++kc) qf[kc] = *(const bf16x8*)(qp + kc * 32);

        f32x4 ctx[8] = {};
        float m_s = -INFINITY, l_s = 0.f;

        stageK(cur, 0);
        stageV(cur, 0);

        for (int kb = 0; kb <= qt; ++kb) {
            __syncthreads();
            if (kb < qt) { stageK(cur ^ 1, kb + 1); stageV(cur ^ 1, kb + 1); }

            const char* kbp = (const char*)&Ks[cur][0];
            f32x4 st[4] = {};
#pragma unroll
            for (int nf = 0; nf < 4; ++nf) {
                int krow = nf * 16 + lc;
#pragma unroll
                for (int kc = 0; kc < 4; ++kc) {
                    bf16x8 kf = *(const bf16x8*)(kbp + krow * 256 + ((kc * 64 + lg * 16) ^ kswz));
                    st[nf] = __builtin_amdgcn_mfma_f32_16x16x32_bf16(kf, qf[kc], st[nf], 0, 0, 0);
                }
            }

            if (kb == qt) {
                int q = q0 + lc;
#pragma unroll
                for (int nf = 0; nf < 4; ++nf) {
                    int key = kb * 64 + nf * 16 + lg * 4;
#pragma unroll
                    for (int r = 0; r < 4; ++r)
                        if (key + r > q) st[nf][r] = -INFINITY;
                }
            }

            float mx = -INFINITY;
#pragma unroll
            for (int nf = 0; nf < 4; ++nf)
#pragma unroll
                for (int r = 0; r < 4; ++r) mx = fmaxf(mx, st[nf][r]);
            mx = fmaxf(mx, __shfl_xor(mx, 16));
            mx = fmaxf(mx, __shfl_xor(mx, 32));
            float mi = fmaxf(m_s, mx);
            float scv = __expf(m_s - mi);
            m_s = mi;

            float rs = 0.f;
#pragma unroll
            for (int nf = 0; nf < 4; ++nf) {
                float p0 = __expf(st[nf][0] - mi);
                float p1 = __expf(st[nf][1] - mi);
                float p2 = __expf(st[nf][2] - mi);
                float p3 = __expf(st[nf][3] - mi);
                rs += (p0 + p1) + (p2 + p3);
                bf16x4 pv = { (bf16)p0, (bf16)p1, (bf16)p2, (bf16)p3 };
                *(bf16x4*)(pb + lc * 128 + ((nf * 32 + lg * 8) ^ kswz)) = pv;
            }
            rs += __shfl_xor(rs, 16);
            rs += __shfl_xor(rs, 32);
            l_s = l_s * scv + rs;

            float scvr[4];
#pragma unroll
            for (int r = 0; r < 4; ++r) scvr[r] = __shfl(scv, lg * 4 + r);
#pragma unroll
            for (int nd = 0; nd < 8; ++nd)
#pragma unroll
                for (int r = 0; r < 4; ++r) ctx[nd][r] *= scvr[r];

            asm volatile("s_waitcnt lgkmcnt(0)" ::: "memory");
            SBAR();
            bf16x8 pa0 = *(const bf16x8*)(pb + lc * 128 + ((lg * 16) ^ kswz));
            bf16x8 pa1 = *(const bf16x8*)(pb + lc * 128 + ((64 + lg * 16) ^ kswz));

            const char* vb = (const char*)&Vs[cur][0];
#pragma unroll
            for (int nd = 0; nd < 8; ++nd) {
                int vrow = nd * 16 + lc;
#pragma unroll
                for (int k2 = 0; k2 < 2; ++k2) {
                    bf16x8 vf = *(const bf16x8*)(vb + vrow * 128 + ((k2 * 64 + lg * 16) ^ kswz));
                    ctx[nd] = __builtin_amdgcn_mfma_f32_16x16x32_bf16(k2 ? pa1 : pa0, vf, ctx[nd], 0, 0, 0);
                }
            }
            cur ^= 1;
        }

        float lr[4];
#pragma unroll
        for (int r = 0; r < 4; ++r) lr[r] = 1.f / __shfl(l_s, lg * 4 + r);
#pragma unroll
        for (int nd = 0; nd < 8; ++nd)
#pragma unroll
            for (int r = 0; r < 4; ++r)
                O[((size_t)(b * SEQ + q0 + lg * 4 + r)) * D_MODEL + h * HD + nd * 16 + lc] =
                    (bf16)(ctx[nd][r] * lr[r]);
    }
}

// ---------------- launch ----------------
extern "C" void kernel_launch(void* const* d_in, const int* in_sizes, int n_in,
                              void* d_out, int out_size, void* d_ws, size_t ws_size,
                              hipStream_t stream) {
    const float* x  = (const float*)d_in[0];
    const float* Wq = (const float*)d_in[1];
    const float* Wk = (const float*)d_in[2];
    const float* Wv = (const float*)d_in[3];
    const float* Wo = (const float*)d_in[4];

    char* ws = (char*)d_ws;
    bf16* xb   = (bf16*)(ws + 0);            // 16 MB; reused as ctx after QKV GEMM
    bf16* wqkv = (bf16*)(ws + 16777216);     // 24 MB  [6144][2048]
    bf16* wob  = (bf16*)(ws + 41943040);     // 8 MB
    bf16* QKV  = (bf16*)(ws + 50331648);     // 48 MB  [4096][6144]
    bf16* Vtb  = (bf16*)(ws + 100663296);    // 16 MB  [B,H,D,S]
    float* cosd = (float*)(ws + 117440512);
    float* sind = (float*)(ws + 117964800);

    // fused convert: 25165824 elems -> contiguous xb|wqkv|wob
    cvt_all<<<25165824 / 1024, 256, 0, stream>>>(x, Wq, Wk, Wv, Wo, xb);

    rope_tables_k<<<(SEQ * 64) / 256, 256, 0, stream>>>(cosd, sind);

    // fused QKV projection: [4096,2048] x [6144,2048]^T -> [4096,6144]
    // 128x256 tiles: 32x24 = 768 blocks = exactly 3 rounds at 1 block/CU
    gemm128<0><<<dim3(768), 512, 0, stream>>>(
        xb, wqkv, QKV, BATCH * SEQ, QKV_LD, D_MODEL);

    const float qscale = 0.08838834764831845f;  // 1/sqrt(128)
    rope_apply<<<(BATCH * SEQ * 1024) / 256, 256, 0, stream>>>(QKV,           cosd, sind, qscale, QKV_LD);
    rope_apply<<<(BATCH * SEQ * 1024) / 256, 256, 0, stream>>>(QKV + D_MODEL, cosd, sind, 1.0f,   QKV_LD);

    transpose_v<<<dim3(SEQ / 32, HD / 32, BATCH * NH), 256, 0, stream>>>(QKV + 2 * D_MODEL, Vtb, QKV_LD);

    flash_attn<<<dim3(512), 256, 0, stream>>>(QKV, Vtb, xb /*ctx*/);

    // output projection: [4096,2048] x [2048,2048]^T -> d_out (f32)
    // 128x256 tiles: 32x8 = 256 blocks = exactly 1 round
    gemm128<1><<<dim3(256), 512, 0, stream>>>(
        xb, wob, d_out, BATCH * SEQ, D_MODEL, D_MODEL);
}

// Round 13
// 272.356 us; speedup vs baseline: 1.0467x; 1.0467x over previous
//
#include <hip/hip_runtime.h>
#include <hip/hip_bf16.h>
#include <cstdint>
#include <cstddef>

typedef __bf16 bf16;
typedef __bf16 bf16x4 __attribute__((ext_vector_type(4)));
typedef __bf16 bf16x8 __attribute__((ext_vector_type(8)));
typedef float f32x4 __attribute__((ext_vector_type(4)));

#define D_MODEL 2048
#define SEQ     2048
#define NH      16
#define HD      128
#define BATCH   2
#define QKV_LD  6144

#define SBAR()  __builtin_amdgcn_sched_barrier(0)
#define HWBAR() do { SBAR(); __builtin_amdgcn_s_barrier(); SBAR(); } while (0)

// ---------------- async global->LDS 16B ----------------
__device__ __forceinline__ void gld16(void* lds, const void* g) {
    __builtin_amdgcn_global_load_lds(
        (const __attribute__((address_space(1))) unsigned int*)g,
        (__attribute__((address_space(3))) unsigned int*)lds,
        16, 0, 0);
}

// ---------------- fused fp32 -> bf16 convert (x, Wq, Wk, Wv, Wo) ----------------
__global__ __launch_bounds__(256) void cvt_all(const float* __restrict__ x,
                                               const float* __restrict__ Wq,
                                               const float* __restrict__ Wk,
                                               const float* __restrict__ Wv,
                                               const float* __restrict__ Wo,
                                               bf16* __restrict__ out) {
    int i = (blockIdx.x * 256 + threadIdx.x) * 4;  // 25165824 total elems
    const float* src;
    int off;
    if (i < 8388608) { src = x; off = i; }
    else {
        int j = i - 8388608;
        int seg = j >> 22;
        src = (seg == 0) ? Wq : (seg == 1) ? Wk : (seg == 2) ? Wv : Wo;
        off = j & 4194303;
    }
    float4 v = *(const float4*)(src + off);
    bf16* o = out + i;
    o[0] = (bf16)v.x; o[1] = (bf16)v.y; o[2] = (bf16)v.z; o[3] = (bf16)v.w;
}

// ---------------- RoPE tables (cos/sin, S x 64) ----------------
__global__ __launch_bounds__(256) void rope_tables_k(float* __restrict__ cosd,
                                                     float* __restrict__ sind) {
    int id = blockIdx.x * 256 + threadIdx.x;  // SEQ*64
    int s = id >> 6, d = id & 63;
    float freq = powf(10000.f, -(float)d * (1.f / 64.f));
    float a = (float)s * freq;
    float sn, c;
    sincosf(a, &sn, &c);
    cosd[id] = c;
    sind[id] = sn;
}

// ---------------- RoPE apply (in-place, row stride ld) ----------------
__global__ __launch_bounds__(256) void rope_apply(bf16* __restrict__ T,
                                                  const float* __restrict__ cosd,
                                                  const float* __restrict__ sind,
                                                  float scale, int ld) {
    int id = blockIdx.x * 256 + threadIdx.x;   // B*S*NH*64
    int row = id >> 10;                        // B*S
    int p = id & 1023;
    int h = p >> 6, d = p & 63;
    int s = row & (SEQ - 1);
    size_t base = (size_t)row * ld + h * HD + d;
    float x1 = (float)T[base];
    float x2 = (float)T[base + 64];
    float c = cosd[(s << 6) + d];
    float sn = sind[(s << 6) + d];
    T[base]      = (bf16)((x1 * c - x2 * sn) * scale);
    T[base + 64] = (bf16)((x2 * c + x1 * sn) * scale);
}

// ---------------- V transpose: [B,S,(ld)] head cols -> [B,H,D,S] ----------------
__global__ __launch_bounds__(256) void transpose_v(const bf16* __restrict__ V,
                                                   bf16* __restrict__ Vt, int ld) {
    __shared__ bf16 t[32][33];
    int s0 = blockIdx.x * 32;
    int d0 = blockIdx.y * 32;
    int bh = blockIdx.z;
    int b = bh >> 4, h = bh & 15;
    int tx = threadIdx.x & 31, ty = threadIdx.x >> 5;  // ty 0..7
#pragma unroll
    for (int i = 0; i < 32; i += 8)
        t[ty + i][tx] = V[((size_t)(b * SEQ + s0 + ty + i)) * ld + h * HD + d0 + tx];
    __syncthreads();
#pragma unroll
    for (int i = 0; i < 32; i += 8)
        Vt[((size_t)bh * HD + d0 + ty + i) * SEQ + s0 + tx] = t[tx][ty + i];
}

// ---------------- 128x256 NT GEMM, 2-phase pipelined (R11-exact) ----------------
template <int OUTF32>
__global__ __launch_bounds__(512, 2)
void gemm128(const bf16* __restrict__ A, const bf16* __restrict__ B,
             void* __restrict__ Cout, int M, int N, int K) {
    __shared__ __align__(16) bf16 ldsA[2][128 * 64];
    __shared__ __align__(16) bf16 ldsB[2][2][128 * 64];

    const int nN = N >> 8;
    const int cpx = gridDim.x >> 3;
    const int lin = (blockIdx.x & 7) * cpx + (blockIdx.x >> 3);  // XCD-chunked
    const int m0 = (lin / nN) * 128, n0 = (lin % nN) * 256;

    const int tid = threadIdx.x;
    const int w = tid >> 6, l = tid & 63;
    const int wm = w >> 2, wn = w & 3;
    const int lg = l >> 4, lc = l & 15;
    const int swz = (lc & 7) << 4;
    const int NT = K >> 6;

    f32x4 acc[2][4][2] = {};   // [nq][mt][nt]

    auto stageA = [&](int tau) {
        bf16* dst = &ldsA[tau & 1][0];
#pragma unroll
        for (int j = 0; j < 2; ++j) {
            int r = w * 16 + j * 8 + (l >> 3);
            int scb = ((l & 7) * 16) ^ ((r & 7) << 4);
            gld16(dst + (w * 16 + j * 8) * 64, A + (size_t)(m0 + r) * K + tau * 64 + (scb >> 1));
        }
    };
    auto stageB = [&](int tau, int u) {
        bf16* dst = &ldsB[tau & 1][u][0];
#pragma unroll
        for (int j = 0; j < 2; ++j) {
            int r = w * 16 + j * 8 + (l >> 3);
            int scb = ((l & 7) * 16) ^ ((r & 7) << 4);
            gld16(dst + (w * 16 + j * 8) * 64, B + (size_t)(n0 + u * 128 + r) * K + tau * 64 + (scb >> 1));
        }
    };

    // prologue: tile0 fully + A(1); tile0 resident, A(1) in flight
    stageA(0); stageB(0, 0); stageB(0, 1); stageA(1);
    SBAR();
    asm volatile("s_waitcnt vmcnt(2)" ::: "memory");
    HWBAR();

    for (int t = 0; t < NT; ++t) {
        const int c = t & 1;
        const char* Ab = (const char*)&ldsA[c][0];
        const char* Bb = (const char*)&ldsB[c][wn >> 1][0];
        const int brow0 = (wn & 1) * 64;
        bf16x8 Af[4][2], Bf[2][2];

        // ---- phase 0 (nq0): read A + B(nq0); stage B0(t+1) ----
#pragma unroll
        for (int mt = 0; mt < 4; ++mt)
#pragma unroll
            for (int ks = 0; ks < 2; ++ks)
                Af[mt][ks] = *(const bf16x8*)(Ab + (wm * 64 + mt * 16 + lc) * 128 + ((ks * 64 + lg * 16) ^ swz));
#pragma unroll
        for (int nt = 0; nt < 2; ++nt)
#pragma unroll
            for (int ks = 0; ks < 2; ++ks)
                Bf[nt][ks] = *(const bf16x8*)(Bb + (brow0 + nt * 16 + lc) * 128 + ((ks * 64 + lg * 16) ^ swz));
        if (t + 1 < NT) stageB(t + 1, 0);
        HWBAR();
        __builtin_amdgcn_s_setprio(1);
#pragma unroll
        for (int mt = 0; mt < 4; ++mt)
#pragma unroll
            for (int nt = 0; nt < 2; ++nt)
#pragma unroll
                for (int ks = 0; ks < 2; ++ks)
                    acc[0][mt][nt] = __builtin_amdgcn_mfma_f32_16x16x32_bf16(Af[mt][ks], Bf[nt][ks], acc[0][mt][nt], 0, 0, 0);
        __builtin_amdgcn_s_setprio(0);
        HWBAR();

        // ---- phase 1 (nq1): read B(nq1); stage B1(t+1) + A(t+2) ----
#pragma unroll
        for (int nt = 0; nt < 2; ++nt)
#pragma unroll
            for (int ks = 0; ks < 2; ++ks)
                Bf[nt][ks] = *(const bf16x8*)(Bb + (brow0 + 32 + nt * 16 + lc) * 128 + ((ks * 64 + lg * 16) ^ swz));
        if (t + 1 < NT) stageB(t + 1, 1);
        if (t + 2 < NT) stageA(t + 2);
        HWBAR();
        __builtin_amdgcn_s_setprio(1);
#pragma unroll
        for (int mt = 0; mt < 4; ++mt)
#pragma unroll
            for (int nt = 0; nt < 2; ++nt)
#pragma unroll
                for (int ks = 0; ks < 2; ++ks)
                    acc[1][mt][nt] = __builtin_amdgcn_mfma_f32_16x16x32_bf16(Af[mt][ks], Bf[nt][ks], acc[1][mt][nt], 0, 0, 0);
        __builtin_amdgcn_s_setprio(0);
        SBAR();
        if (t + 2 < NT) asm volatile("s_waitcnt vmcnt(2)" ::: "memory");
        else            asm volatile("s_waitcnt vmcnt(0)" ::: "memory");
        HWBAR();
    }

    // ---- epilogue ----
#pragma unroll
    for (int nq = 0; nq < 2; ++nq)
#pragma unroll
        for (int mt = 0; mt < 4; ++mt)
#pragma unroll
            for (int nt = 0; nt < 2; ++nt)
#pragma unroll
                for (int rr = 0; rr < 4; ++rr) {
                    size_t row = (size_t)m0 + wm * 64 + mt * 16 + lg * 4 + rr;
                    size_t col = (size_t)n0 + wn * 64 + nq * 32 + nt * 16 + lc;
                    float v = acc[nq][mt][nt][rr];
                    if (OUTF32) ((float*)Cout)[row * N + col] = v;
                    else        ((bf16*)Cout)[row * N + col] = (bf16)v;
                }
}

// ---------------- Flash attention: + defer-max (T13) + max3 tree ----------------
__global__ __launch_bounds__(256)
void flash_attn(const bf16* __restrict__ QKV, const bf16* __restrict__ Vt,
                bf16* __restrict__ O) {
    __shared__ __align__(16) bf16 Ks[2][64 * 128];   // [key][d], rows 256B
    __shared__ __align__(16) bf16 Vs[2][128 * 64];   // [d][key], rows 128B
    __shared__ __align__(16) bf16 p_lds[4][16 * 64]; // per-wave P[q][key], rows 128B

    const int bid = blockIdx.x;                   // 512
    const int lin = (bid & 7) * 64 + (bid >> 3);  // XCD-chunked
    const int bh = lin >> 4;
    const int jj = lin & 15;
    const int b = bh >> 4, h = bh & 15;

    const int tid = threadIdx.x;
    const int w = tid >> 6, l = tid & 63;
    const int lg = l >> 4, lc = l & 15;
    const int kswz = (lc & 7) << 4;
    char* pb = (char*)&p_lds[w][0];

    auto stageK = [&](int p, int kb) {
#pragma unroll
        for (int c = 0; c < 4; ++c) {
            int r = c * 16 + w * 4 + (l >> 4);
            int scb = ((l & 15) * 16) ^ ((r & 7) << 4);
            const bf16* g = QKV + ((size_t)(b * SEQ + kb * 64 + r)) * QKV_LD + D_MODEL + h * HD + (scb >> 1);
            gld16(&Ks[p][(c * 16 + w * 4) * 128], g);
        }
    };
    auto stageV = [&](int p, int kb) {
#pragma unroll
        for (int c = 0; c < 4; ++c) {
            int r = c * 32 + w * 8 + (l >> 3);
            int scb = ((l & 7) * 16) ^ ((r & 7) << 4);
            const bf16* g = Vt + ((size_t)bh * HD + r) * SEQ + kb * 64 + (scb >> 1);
            gld16(&Vs[p][(c * 32 + w * 8) * 64], g);
        }
    };

    int cur = 0;
#pragma unroll 1
    for (int ti = 0; ti < 2; ++ti) {
        const int qt = ti ? jj : (31 - jj);       // long tile first
        const int q0 = qt * 64 + w * 16;

        const bf16* qp = QKV + ((size_t)(b * SEQ + q0 + lc)) * QKV_LD + h * HD + lg * 8;
        bf16x8 qf[4];
#pragma unroll
        for (int kc = 0; kc < 4; ++kc) qf[kc] = *(const bf16x8*)(qp + kc * 32);

        f32x4 ctx[8] = {};
        float m_s = -INFINITY, l_s = 0.f;

        stageK(cur, 0);
        stageV(cur, 0);

        for (int kb = 0; kb <= qt; ++kb) {
            __syncthreads();
            if (kb < qt) { stageK(cur ^ 1, kb + 1); stageV(cur ^ 1, kb + 1); }

            const char* kbp = (const char*)&Ks[cur][0];
            f32x4 st[4] = {};
#pragma unroll
            for (int nf = 0; nf < 4; ++nf) {
                int krow = nf * 16 + lc;
#pragma unroll
                for (int kc = 0; kc < 4; ++kc) {
                    bf16x8 kf = *(const bf16x8*)(kbp + krow * 256 + ((kc * 64 + lg * 16) ^ kswz));
                    st[nf] = __builtin_amdgcn_mfma_f32_16x16x32_bf16(kf, qf[kc], st[nf], 0, 0, 0);
                }
            }

            if (kb == qt) {
                int q = q0 + lc;
#pragma unroll
                for (int nf = 0; nf < 4; ++nf) {
                    int key = kb * 64 + nf * 16 + lg * 4;
#pragma unroll
                    for (int r = 0; r < 4; ++r)
                        if (key + r > q) st[nf][r] = -INFINITY;
                }
            }

            // row max: max3 tree over the 16 in-lane values, then 2 shfl stages
            float m01 = fmaxf(fmaxf(st[0][0], st[0][1]), fmaxf(st[0][2], st[0][3]));
            float m23 = fmaxf(fmaxf(st[1][0], st[1][1]), fmaxf(st[1][2], st[1][3]));
            float m45 = fmaxf(fmaxf(st[2][0], st[2][1]), fmaxf(st[2][2], st[2][3]));
            float m67 = fmaxf(fmaxf(st[3][0], st[3][1]), fmaxf(st[3][2], st[3][3]));
            float mx = fmaxf(fmaxf(m01, m23), fmaxf(m45, m67));
            mx = fmaxf(mx, __shfl_xor(mx, 16));
            mx = fmaxf(mx, __shfl_xor(mx, 32));

            // T13 defer-max: skip rescale while max growth <= 8 (P bounded by e^8)
            bool defer = __all(mx <= m_s + 8.f) && (m_s > -INFINITY);
            float mi;
            if (defer) {
                mi = m_s;                         // keep old max, scv == 1
            } else {
                mi = fmaxf(m_s, mx);
                float scv = __expf(m_s - mi);
                float scvr[4];
#pragma unroll
                for (int r = 0; r < 4; ++r) scvr[r] = __shfl(scv, lg * 4 + r);
#pragma unroll
                for (int nd = 0; nd < 8; ++nd)
#pragma unroll
                    for (int r = 0; r < 4; ++r) ctx[nd][r] *= scvr[r];
                l_s *= scv;
                m_s = mi;
            }

            float rs = 0.f;
#pragma unroll
            for (int nf = 0; nf < 4; ++nf) {
                float p0 = __expf(st[nf][0] - mi);
                float p1 = __expf(st[nf][1] - mi);
                float p2 = __expf(st[nf][2] - mi);
                float p3 = __expf(st[nf][3] - mi);
                rs += (p0 + p1) + (p2 + p3);
                bf16x4 pv = { (bf16)p0, (bf16)p1, (bf16)p2, (bf16)p3 };
                *(bf16x4*)(pb + lc * 128 + ((nf * 32 + lg * 8) ^ kswz)) = pv;
            }
            rs += __shfl_xor(rs, 16);
            rs += __shfl_xor(rs, 32);
            l_s += rs;

            asm volatile("s_waitcnt lgkmcnt(0)" ::: "memory");
            SBAR();
            bf16x8 pa0 = *(const bf16x8*)(pb + lc * 128 + ((lg * 16) ^ kswz));
            bf16x8 pa1 = *(const bf16x8*)(pb + lc * 128 + ((64 + lg * 16) ^ kswz));

            const char* vb = (const char*)&Vs[cur][0];
#pragma unroll
            for (int nd = 0; nd < 8; ++nd) {
                int vrow = nd * 16 + lc;
#pragma unroll
                for (int k2 = 0; k2 < 2; ++k2) {
                    bf16x8 vf = *(const bf16x8*)(vb + vrow * 128 + ((k2 * 64 + lg * 16) ^ kswz));
                    ctx[nd] = __builtin_amdgcn_mfma_f32_16x16x32_bf16(k2 ? pa1 : pa0, vf, ctx[nd], 0, 0, 0);
                }
            }
            cur ^= 1;
        }

        float lr[4];
#pragma unroll
        for (int r = 0; r < 4; ++r) lr[r] = 1.f / __shfl(l_s, lg * 4 + r);
#pragma unroll
        for (int nd = 0; nd < 8; ++nd)
#pragma unroll
            for (int r = 0; r < 4; ++r)
                O[((size_t)(b * SEQ + q0 + lg * 4 + r)) * D_MODEL + h * HD + nd * 16 + lc] =
                    (bf16)(ctx[nd][r] * lr[r]);
    }
}

// ---------------- launch ----------------
extern "C" void kernel_launch(void* const* d_in, const int* in_sizes, int n_in,
                              void* d_out, int out_size, void* d_ws, size_t ws_size,
                              hipStream_t stream) {
    const float* x  = (const float*)d_in[0];
    const float* Wq = (const float*)d_in[1];
    const float* Wk = (const float*)d_in[2];
    const float* Wv = (const float*)d_in[3];
    const float* Wo = (const float*)d_in[4];

    char* ws = (char*)d_ws;
    bf16* xb   = (bf16*)(ws + 0);            // 16 MB; reused as ctx after QKV GEMM
    bf16* wqkv = (bf16*)(ws + 16777216);     // 24 MB  [6144][2048]
    bf16* wob  = (bf16*)(ws + 41943040);     // 8 MB
    bf16* QKV  = (bf16*)(ws + 50331648);     // 48 MB  [4096][6144]
    bf16* Vtb  = (bf16*)(ws + 100663296);    // 16 MB  [B,H,D,S]
    float* cosd = (float*)(ws + 117440512);
    float* sind = (float*)(ws + 117964800);

    // fused convert: 25165824 elems -> contiguous xb|wqkv|wob
    cvt_all<<<25165824 / 1024, 256, 0, stream>>>(x, Wq, Wk, Wv, Wo, xb);

    rope_tables_k<<<(SEQ * 64) / 256, 256, 0, stream>>>(cosd, sind);

    // fused QKV projection: [4096,2048] x [6144,2048]^T -> [4096,6144]
    gemm128<0><<<dim3(768), 512, 0, stream>>>(
        xb, wqkv, QKV, BATCH * SEQ, QKV_LD, D_MODEL);

    const float qscale = 0.08838834764831845f;  // 1/sqrt(128)
    rope_apply<<<(BATCH * SEQ * 1024) / 256, 256, 0, stream>>>(QKV,           cosd, sind, qscale, QKV_LD);
    rope_apply<<<(BATCH * SEQ * 1024) / 256, 256, 0, stream>>>(QKV + D_MODEL, cosd, sind, 1.0f,   QKV_LD);

    transpose_v<<<dim3(SEQ / 32, HD / 32, BATCH * NH), 256, 0, stream>>>(QKV + 2 * D_MODEL, Vtb, QKV_LD);

    flash_attn<<<dim3(512), 256, 0, stream>>>(QKV, Vtb, xb /*ctx*/);

    // output projection: [4096,2048] x [2048,2048]^T -> d_out (f32)
    gemm128<1><<<dim3(256), 512, 0, stream>>>(
        xb, wob, d_out, BATCH * SEQ, D_MODEL, D_MODEL);
}

// Round 16
// 269.590 us; speedup vs baseline: 1.0575x; 1.0103x over previous
//
#include <hip/hip_runtime.h>
#include <hip/hip_bf16.h>
#include <cstdint>
#include <cstddef>

typedef __bf16 bf16;
typedef __bf16 bf16x4 __attribute__((ext_vector_type(4)));
typedef __bf16 bf16x8 __attribute__((ext_vector_type(8)));
typedef float f32x4 __attribute__((ext_vector_type(4)));

#define D_MODEL 2048
#define SEQ     2048
#define NH      16
#define HD      128
#define BATCH   2
#define QKV_LD  6144

#define SBAR()  __builtin_amdgcn_sched_barrier(0)
#define HWBAR() do { SBAR(); __builtin_amdgcn_s_barrier(); SBAR(); } while (0)

// ---------------- async global->LDS 16B ----------------
__device__ __forceinline__ void gld16(void* lds, const void* g) {
    __builtin_amdgcn_global_load_lds(
        (const __attribute__((address_space(1))) unsigned int*)g,
        (__attribute__((address_space(3))) unsigned int*)lds,
        16, 0, 0);
}

// ---------------- fused fp32 -> bf16 convert (x, Wq, Wk, Wv, Wo) ----------------
__global__ __launch_bounds__(256) void cvt_all(const float* __restrict__ x,
                                               const float* __restrict__ Wq,
                                               const float* __restrict__ Wk,
                                               const float* __restrict__ Wv,
                                               const float* __restrict__ Wo,
                                               bf16* __restrict__ out) {
    int i = (blockIdx.x * 256 + threadIdx.x) * 4;  // 25165824 total elems
    const float* src;
    int off;
    if (i < 8388608) { src = x; off = i; }
    else {
        int j = i - 8388608;
        int seg = j >> 22;
        src = (seg == 0) ? Wq : (seg == 1) ? Wk : (seg == 2) ? Wv : Wo;
        off = j & 4194303;
    }
    float4 v = *(const float4*)(src + off);
    bf16* o = out + i;
    o[0] = (bf16)v.x; o[1] = (bf16)v.y; o[2] = (bf16)v.z; o[3] = (bf16)v.w;
}

// ---------------- RoPE tables (cos/sin, S x 64) ----------------
__global__ __launch_bounds__(256) void rope_tables_k(float* __restrict__ cosd,
                                                     float* __restrict__ sind) {
    int id = blockIdx.x * 256 + threadIdx.x;  // SEQ*64
    int s = id >> 6, d = id & 63;
    float freq = powf(10000.f, -(float)d * (1.f / 64.f));
    float a = (float)s * freq;
    float sn, c;
    sincosf(a, &sn, &c);
    cosd[id] = c;
    sind[id] = sn;
}

// ---------------- RoPE apply, Q and K regions in one launch ----------------
// total threads = 2 * B*S*NH*64 = 2^23; per-half = 2^22.
__global__ __launch_bounds__(256) void rope_apply2(bf16* __restrict__ T,
                                                   const float* __restrict__ cosd,
                                                   const float* __restrict__ sind,
                                                   float qscale) {
    int id = blockIdx.x * 256 + threadIdx.x;
    int half = id >> 22;                       // 0 = Q, 1 = K
    int jd = id & 4194303;                     // 2^22 - 1
    int row = jd >> 10;                        // B*S
    int p = jd & 1023;
    int h = p >> 6, d = p & 63;
    int s = row & (SEQ - 1);
    size_t base = (size_t)row * QKV_LD + half * D_MODEL + h * HD + d;
    float scale = half ? 1.0f : qscale;
    float x1 = (float)T[base];
    float x2 = (float)T[base + 64];
    float c = cosd[(s << 6) + d];
    float sn = sind[(s << 6) + d];
    T[base]      = (bf16)((x1 * c - x2 * sn) * scale);
    T[base + 64] = (bf16)((x2 * c + x1 * sn) * scale);
}

// ---------------- V transpose: [B,S,(ld)] head cols -> [B,H,D,S] ----------------
__global__ __launch_bounds__(256) void transpose_v(const bf16* __restrict__ V,
                                                   bf16* __restrict__ Vt, int ld) {
    __shared__ bf16 t[32][33];
    int s0 = blockIdx.x * 32;
    int d0 = blockIdx.y * 32;
    int bh = blockIdx.z;
    int b = bh >> 4, h = bh & 15;
    int tx = threadIdx.x & 31, ty = threadIdx.x >> 5;  // ty 0..7
#pragma unroll
    for (int i = 0; i < 32; i += 8)
        t[ty + i][tx] = V[((size_t)(b * SEQ + s0 + ty + i)) * ld + h * HD + d0 + tx];
    __syncthreads();
#pragma unroll
    for (int i = 0; i < 32; i += 8)
        Vt[((size_t)bh * HD + d0 + ty + i) * SEQ + s0 + tx] = t[tx][ty + i];
}

// ---------------- 128x256 NT GEMM, 2-phase pipelined (R11-exact) ----------------
template <int OUTF32>
__global__ __launch_bounds__(512, 2)
void gemm128(const bf16* __restrict__ A, const bf16* __restrict__ B,
             void* __restrict__ Cout, int M, int N, int K) {
    __shared__ __align__(16) bf16 ldsA[2][128 * 64];
    __shared__ __align__(16) bf16 ldsB[2][2][128 * 64];

    const int nN = N >> 8;
    const int cpx = gridDim.x >> 3;
    const int lin = (blockIdx.x & 7) * cpx + (blockIdx.x >> 3);  // XCD-chunked
    const int m0 = (lin / nN) * 128, n0 = (lin % nN) * 256;

    const int tid = threadIdx.x;
    const int w = tid >> 6, l = tid & 63;
    const int wm = w >> 2, wn = w & 3;
    const int lg = l >> 4, lc = l & 15;
    const int swz = (lc & 7) << 4;
    const int NT = K >> 6;

    f32x4 acc[2][4][2] = {};   // [nq][mt][nt]

    auto stageA = [&](int tau) {
        bf16* dst = &ldsA[tau & 1][0];
#pragma unroll
        for (int j = 0; j < 2; ++j) {
            int r = w * 16 + j * 8 + (l >> 3);
            int scb = ((l & 7) * 16) ^ ((r & 7) << 4);
            gld16(dst + (w * 16 + j * 8) * 64, A + (size_t)(m0 + r) * K + tau * 64 + (scb >> 1));
        }
    };
    auto stageB = [&](int tau, int u) {
        bf16* dst = &ldsB[tau & 1][u][0];
#pragma unroll
        for (int j = 0; j < 2; ++j) {
            int r = w * 16 + j * 8 + (l >> 3);
            int scb = ((l & 7) * 16) ^ ((r & 7) << 4);
            gld16(dst + (w * 16 + j * 8) * 64, B + (size_t)(n0 + u * 128 + r) * K + tau * 64 + (scb >> 1));
        }
    };

    // prologue: tile0 fully + A(1); tile0 resident, A(1) in flight
    stageA(0); stageB(0, 0); stageB(0, 1); stageA(1);
    SBAR();
    asm volatile("s_waitcnt vmcnt(2)" ::: "memory");
    HWBAR();

    for (int t = 0; t < NT; ++t) {
        const int c = t & 1;
        const char* Ab = (const char*)&ldsA[c][0];
        const char* Bb = (const char*)&ldsB[c][wn >> 1][0];
        const int brow0 = (wn & 1) * 64;
        bf16x8 Af[4][2], Bf[2][2];

        // ---- phase 0 (nq0): read A + B(nq0); stage B0(t+1) ----
#pragma unroll
        for (int mt = 0; mt < 4; ++mt)
#pragma unroll
            for (int ks = 0; ks < 2; ++ks)
                Af[mt][ks] = *(const bf16x8*)(Ab + (wm * 64 + mt * 16 + lc) * 128 + ((ks * 64 + lg * 16) ^ swz));
#pragma unroll
        for (int nt = 0; nt < 2; ++nt)
#pragma unroll
            for (int ks = 0; ks < 2; ++ks)
                Bf[nt][ks] = *(const bf16x8*)(Bb + (brow0 + nt * 16 + lc) * 128 + ((ks * 64 + lg * 16) ^ swz));
        if (t + 1 < NT) stageB(t + 1, 0);
        HWBAR();
        __builtin_amdgcn_s_setprio(1);
#pragma unroll
        for (int mt = 0; mt < 4; ++mt)
#pragma unroll
            for (int nt = 0; nt < 2; ++nt)
#pragma unroll
                for (int ks = 0; ks < 2; ++ks)
                    acc[0][mt][nt] = __builtin_amdgcn_mfma_f32_16x16x32_bf16(Af[mt][ks], Bf[nt][ks], acc[0][mt][nt], 0, 0, 0);
        __builtin_amdgcn_s_setprio(0);
        HWBAR();

        // ---- phase 1 (nq1): read B(nq1); stage B1(t+1) + A(t+2) ----
#pragma unroll
        for (int nt = 0; nt < 2; ++nt)
#pragma unroll
            for (int ks = 0; ks < 2; ++ks)
                Bf[nt][ks] = *(const bf16x8*)(Bb + (brow0 + 32 + nt * 16 + lc) * 128 + ((ks * 64 + lg * 16) ^ swz));
        if (t + 1 < NT) stageB(t + 1, 1);
        if (t + 2 < NT) stageA(t + 2);
        HWBAR();
        __builtin_amdgcn_s_setprio(1);
#pragma unroll
        for (int mt = 0; mt < 4; ++mt)
#pragma unroll
            for (int nt = 0; nt < 2; ++nt)
#pragma unroll
                for (int ks = 0; ks < 2; ++ks)
                    acc[1][mt][nt] = __builtin_amdgcn_mfma_f32_16x16x32_bf16(Af[mt][ks], Bf[nt][ks], acc[1][mt][nt], 0, 0, 0);
        __builtin_amdgcn_s_setprio(0);
        SBAR();
        if (t + 2 < NT) asm volatile("s_waitcnt vmcnt(2)" ::: "memory");
        else            asm volatile("s_waitcnt vmcnt(0)" ::: "memory");
        HWBAR();
    }

    // ---- epilogue ----
#pragma unroll
    for (int nq = 0; nq < 2; ++nq)
#pragma unroll
        for (int mt = 0; mt < 4; ++mt)
#pragma unroll
            for (int nt = 0; nt < 2; ++nt)
#pragma unroll
                for (int rr = 0; rr < 4; ++rr) {
                    size_t row = (size_t)m0 + wm * 64 + mt * 16 + lg * 4 + rr;
                    size_t col = (size_t)n0 + wn * 64 + nq * 32 + nt * 16 + lc;
                    float v = acc[nq][mt][nt][rr];
                    if (OUTF32) ((float*)Cout)[row * N + col] = v;
                    else        ((bf16*)Cout)[row * N + col] = (bf16)v;
                }
}

// ---------------- Flash attention: QBLK=128, 8 waves, defer-max ----------------
// 256 blocks: (bh, j) pairs 128-row q-tiles {15-j, j} -> 34 iterations each.
// Swapped MFMA: st = mfma(kf, qf); lane (lg,lc) holds S[q=q0+lc][16 keys].
__global__ __launch_bounds__(512)
void flash_attn(const bf16* __restrict__ QKV, const bf16* __restrict__ Vt,
                bf16* __restrict__ O) {
    __shared__ __align__(16) bf16 Ks[2][64 * 128];   // [key][d], rows 256B (32 KB)
    __shared__ __align__(16) bf16 Vs[2][128 * 64];   // [d][key], rows 128B (32 KB)
    __shared__ __align__(16) bf16 p_lds[8][16 * 64]; // per-wave P[q][key] (16 KB)

    const int bid = blockIdx.x;                   // 256
    const int lin = (bid & 7) * 32 + (bid >> 3);  // XCD-chunked
    const int bh = lin >> 3;
    const int jj = lin & 7;
    const int b = bh >> 4, h = bh & 15;

    const int tid = threadIdx.x;
    const int w = tid >> 6, l = tid & 63;         // w 0..7
    const int lg = l >> 4, lc = l & 15;
    const int kswz = (lc & 7) << 4;
    char* pb = (char*)&p_lds[w][0];

    auto stageK = [&](int p, int kb) {
#pragma unroll
        for (int c = 0; c < 2; ++c) {
            int r = c * 32 + w * 4 + (l >> 4);
            int scb = ((l & 15) * 16) ^ ((r & 7) << 4);
            const bf16* g = QKV + ((size_t)(b * SEQ + kb * 64 + r)) * QKV_LD + D_MODEL + h * HD + (scb >> 1);
            gld16(&Ks[p][(c * 32 + w * 4) * 128], g);
        }
    };
    auto stageV = [&](int p, int kb) {
#pragma unroll
        for (int c = 0; c < 2; ++c) {
            int r = c * 64 + w * 8 + (l >> 3);
            int scb = ((l & 7) * 16) ^ ((r & 7) << 4);
            const bf16* g = Vt + ((size_t)bh * HD + r) * SEQ + kb * 64 + (scb >> 1);
            gld16(&Vs[p][(c * 64 + w * 8) * 64], g);
        }
    };

    int cur = 0;
#pragma unroll 1
    for (int ti = 0; ti < 2; ++ti) {
        const int qt = ti ? jj : (15 - jj);       // long tile first
        const int q0 = qt * 128 + w * 16;
        const int kbmax = 2 * qt + 1;             // last key block index

        const bf16* qp = QKV + ((size_t)(b * SEQ + q0 + lc)) * QKV_LD + h * HD + lg * 8;
        bf16x8 qf[4];
#pragma unroll
        for (int kc = 0; kc < 4; ++kc) qf[kc] = *(const bf16x8*)(qp + kc * 32);

        f32x4 ctx[8] = {};
        float m_s = -INFINITY, l_s = 0.f;

        stageK(cur, 0);
        stageV(cur, 0);

        for (int kb = 0; kb <= kbmax; ++kb) {
            __syncthreads();
            if (kb < kbmax) { stageK(cur ^ 1, kb + 1); stageV(cur ^ 1, kb + 1); }

            const char* kbp = (const char*)&Ks[cur][0];
            f32x4 st[4] = {};
#pragma unroll
            for (int nf = 0; nf < 4; ++nf) {
                int krow = nf * 16 + lc;
#pragma unroll
                for (int kc = 0; kc < 4; ++kc) {
                    bf16x8 kf = *(const bf16x8*)(kbp + krow * 256 + ((kc * 64 + lg * 16) ^ kswz));
                    st[nf] = __builtin_amdgcn_mfma_f32_16x16x32_bf16(kf, qf[kc], st[nf], 0, 0, 0);
                }
            }

            if (kb >= 2 * qt) {  // diagonal region: mask key > q
                int q = q0 + lc;
#pragma unroll
                for (int nf = 0; nf < 4; ++nf) {
                    int key = kb * 64 + nf * 16 + lg * 4;
#pragma unroll
                    for (int r = 0; r < 4; ++r)
                        if (key + r > q) st[nf][r] = -INFINITY;
                }
            }

            // row max: in-lane tree + 2 shfl stages
            float m01 = fmaxf(fmaxf(st[0][0], st[0][1]), fmaxf(st[0][2], st[0][3]));
            float m23 = fmaxf(fmaxf(st[1][0], st[1][1]), fmaxf(st[1][2], st[1][3]));
            float m45 = fmaxf(fmaxf(st[2][0], st[2][1]), fmaxf(st[2][2], st[2][3]));
            float m67 = fmaxf(fmaxf(st[3][0], st[3][1]), fmaxf(st[3][2], st[3][3]));
            float mx = fmaxf(fmaxf(m01, m23), fmaxf(m45, m67));
            mx = fmaxf(mx, __shfl_xor(mx, 16));
            mx = fmaxf(mx, __shfl_xor(mx, 32));

            // T13 defer-max: skip rescale while max growth <= 8 (P bounded by e^8)
            bool defer = __all(mx <= m_s + 8.f) && (m_s > -INFINITY);
            float mi;
            if (defer) {
                mi = m_s;
            } else {
                mi = fmaxf(m_s, mx);
                float scv = __expf(m_s - mi);
                float scvr[4];
#pragma unroll
                for (int r = 0; r < 4; ++r) scvr[r] = __shfl(scv, lg * 4 + r);
#pragma unroll
                for (int nd = 0; nd < 8; ++nd)
#pragma unroll
                    for (int r = 0; r < 4; ++r) ctx[nd][r] *= scvr[r];
                l_s *= scv;
                m_s = mi;
            }

            float rs = 0.f;
#pragma unroll
            for (int nf = 0; nf < 4; ++nf) {
                float p0 = __expf(st[nf][0] - mi);
                float p1 = __expf(st[nf][1] - mi);
                float p2 = __expf(st[nf][2] - mi);
                float p3 = __expf(st[nf][3] - mi);
                rs += (p0 + p1) + (p2 + p3);
                bf16x4 pv = { (bf16)p0, (bf16)p1, (bf16)p2, (bf16)p3 };
                *(bf16x4*)(pb + lc * 128 + ((nf * 32 + lg * 8) ^ kswz)) = pv;
            }
            rs += __shfl_xor(rs, 16);
            rs += __shfl_xor(rs, 32);
            l_s += rs;

            asm volatile("s_waitcnt lgkmcnt(0)" ::: "memory");
            SBAR();
            bf16x8 pa0 = *(const bf16x8*)(pb + lc * 128 + ((lg * 16) ^ kswz));
            bf16x8 pa1 = *(const bf16x8*)(pb + lc * 128 + ((64 + lg * 16) ^ kswz));

            const char* vb = (const char*)&Vs[cur][0];
#pragma unroll
            for (int nd = 0; nd < 8; ++nd) {
                int vrow = nd * 16 + lc;
#pragma unroll
                for (int k2 = 0; k2 < 2; ++k2) {
                    bf16x8 vf = *(const bf16x8*)(vb + vrow * 128 + ((k2 * 64 + lg * 16) ^ kswz));
                    ctx[nd] = __builtin_amdgcn_mfma_f32_16x16x32_bf16(k2 ? pa1 : pa0, vf, ctx[nd], 0, 0, 0);
                }
            }
            cur ^= 1;
        }

        float lr[4];
#pragma unroll
        for (int r = 0; r < 4; ++r) lr[r] = 1.f / __shfl(l_s, lg * 4 + r);
#pragma unroll
        for (int nd = 0; nd < 8; ++nd)
#pragma unroll
            for (int r = 0; r < 4; ++r)
                O[((size_t)(b * SEQ + q0 + lg * 4 + r)) * D_MODEL + h * HD + nd * 16 + lc] =
                    (bf16)(ctx[nd][r] * lr[r]);
    }
}

// ---------------- launch ----------------
extern "C" void kernel_launch(void* const* d_in, const int* in_sizes, int n_in,
                              void* d_out, int out_size, void* d_ws, size_t ws_size,
                              hipStream_t stream) {
    const float* x  = (const float*)d_in[0];
    const float* Wq = (const float*)d_in[1];
    const float* Wk = (const float*)d_in[2];
    const float* Wv = (const float*)d_in[3];
    const float* Wo = (const float*)d_in[4];

    char* ws = (char*)d_ws;
    bf16* xb   = (bf16*)(ws + 0);            // 16 MB; reused as ctx after QKV GEMM
    bf16* wqkv = (bf16*)(ws + 16777216);     // 24 MB  [6144][2048]
    bf16* wob  = (bf16*)(ws + 41943040);     // 8 MB
    bf16* QKV  = (bf16*)(ws + 50331648);     // 48 MB  [4096][6144]
    bf16* Vtb  = (bf16*)(ws + 100663296);    // 16 MB  [B,H,D,S]
    float* cosd = (float*)(ws + 117440512);
    float* sind = (float*)(ws + 117964800);

    // fused convert: 25165824 elems -> contiguous xb|wqkv|wob
    cvt_all<<<25165824 / 1024, 256, 0, stream>>>(x, Wq, Wk, Wv, Wo, xb);

    rope_tables_k<<<(SEQ * 64) / 256, 256, 0, stream>>>(cosd, sind);

    // fused QKV projection: [4096,2048] x [6144,2048]^T -> [4096,6144]
    gemm128<0><<<dim3(768), 512, 0, stream>>>(
        xb, wqkv, QKV, BATCH * SEQ, QKV_LD, D_MODEL);

    const float qscale = 0.08838834764831845f;  // 1/sqrt(128)
    rope_apply2<<<(2 * BATCH * SEQ * 1024) / 256, 256, 0, stream>>>(QKV, cosd, sind, qscale);

    transpose_v<<<dim3(SEQ / 32, HD / 32, BATCH * NH), 256, 0, stream>>>(QKV + 2 * D_MODEL, Vtb, QKV_LD);

    flash_attn<<<dim3(256), 512, 0, stream>>>(QKV, Vtb, xb /*ctx*/);

    // output projection: [4096,2048] x [2048,2048]^T -> d_out (f32)
    gemm128<1><<<dim3(256), 512, 0, stream>>>(
        xb, wob, d_out, BATCH * SEQ, D_MODEL, D_MODEL);
}

// Round 17
// 269.080 us; speedup vs baseline: 1.0595x; 1.0019x over previous
//
#include <hip/hip_runtime.h>
#include <hip/hip_bf16.h>
#include <cstdint>
#include <cstddef>

typedef __bf16 bf16;
typedef __bf16 bf16x4 __attribute__((ext_vector_type(4)));
typedef __bf16 bf16x8 __attribute__((ext_vector_type(8)));
typedef float f32x4 __attribute__((ext_vector_type(4)));

#define D_MODEL 2048
#define SEQ     2048
#define NH      16
#define HD      128
#define BATCH   2
#define QKV_LD  6144

#define SBAR()  __builtin_amdgcn_sched_barrier(0)
#define HWBAR() do { SBAR(); __builtin_amdgcn_s_barrier(); SBAR(); } while (0)

// ---------------- async global->LDS 16B ----------------
__device__ __forceinline__ void gld16(void* lds, const void* g) {
    __builtin_amdgcn_global_load_lds(
        (const __attribute__((address_space(1))) unsigned int*)g,
        (__attribute__((address_space(3))) unsigned int*)lds,
        16, 0, 0);
}

// ---------------- fused fp32 -> bf16 convert (x, Wq, Wk, Wv, Wo) ----------------
__global__ __launch_bounds__(256) void cvt_all(const float* __restrict__ x,
                                               const float* __restrict__ Wq,
                                               const float* __restrict__ Wk,
                                               const float* __restrict__ Wv,
                                               const float* __restrict__ Wo,
                                               bf16* __restrict__ out) {
    int i = (blockIdx.x * 256 + threadIdx.x) * 4;  // 25165824 total elems
    const float* src;
    int off;
    if (i < 8388608) { src = x; off = i; }
    else {
        int j = i - 8388608;
        int seg = j >> 22;
        src = (seg == 0) ? Wq : (seg == 1) ? Wk : (seg == 2) ? Wv : Wo;
        off = j & 4194303;
    }
    float4 v = *(const float4*)(src + off);
    bf16* o = out + i;
    o[0] = (bf16)v.x; o[1] = (bf16)v.y; o[2] = (bf16)v.z; o[3] = (bf16)v.w;
}

// ---------------- RoPE tables (cos/sin, S x 64) ----------------
__global__ __launch_bounds__(256) void rope_tables_k(float* __restrict__ cosd,
                                                     float* __restrict__ sind) {
    int id = blockIdx.x * 256 + threadIdx.x;  // SEQ*64
    int s = id >> 6, d = id & 63;
    float freq = powf(10000.f, -(float)d * (1.f / 64.f));
    float a = (float)s * freq;
    float sn, c;
    sincosf(a, &sn, &c);
    cosd[id] = c;
    sind[id] = sn;
}

// ---------------- RoPE apply, Q and K regions in one launch ----------------
// total threads = 2 * B*S*NH*64 = 2^23; per-half = 2^22.
__global__ __launch_bounds__(256) void rope_apply2(bf16* __restrict__ T,
                                                   const float* __restrict__ cosd,
                                                   const float* __restrict__ sind,
                                                   float qscale) {
    int id = blockIdx.x * 256 + threadIdx.x;
    int half = id >> 22;                       // 0 = Q, 1 = K
    int jd = id & 4194303;                     // 2^22 - 1
    int row = jd >> 10;                        // B*S
    int p = jd & 1023;
    int h = p >> 6, d = p & 63;
    int s = row & (SEQ - 1);
    size_t base = (size_t)row * QKV_LD + half * D_MODEL + h * HD + d;
    float scale = half ? 1.0f : qscale;
    float x1 = (float)T[base];
    float x2 = (float)T[base + 64];
    float c = cosd[(s << 6) + d];
    float sn = sind[(s << 6) + d];
    T[base]      = (bf16)((x1 * c - x2 * sn) * scale);
    T[base + 64] = (bf16)((x2 * c + x1 * sn) * scale);
}

// ---------------- V transpose: [B,S,(ld)] head cols -> [B,H,D,S] ----------------
__global__ __launch_bounds__(256) void transpose_v(const bf16* __restrict__ V,
                                                   bf16* __restrict__ Vt, int ld) {
    __shared__ bf16 t[32][33];
    int s0 = blockIdx.x * 32;
    int d0 = blockIdx.y * 32;
    int bh = blockIdx.z;
    int b = bh >> 4, h = bh & 15;
    int tx = threadIdx.x & 31, ty = threadIdx.x >> 5;  // ty 0..7
#pragma unroll
    for (int i = 0; i < 32; i += 8)
        t[ty + i][tx] = V[((size_t)(b * SEQ + s0 + ty + i)) * ld + h * HD + d0 + tx];
    __syncthreads();
#pragma unroll
    for (int i = 0; i < 32; i += 8)
        Vt[((size_t)bh * HD + d0 + ty + i) * SEQ + s0 + tx] = t[tx][ty + i];
}

// ---------------- 128x256 NT GEMM, 2-phase pipelined (R11-exact) ----------------
template <int OUTF32>
__global__ __launch_bounds__(512, 2)
void gemm128(const bf16* __restrict__ A, const bf16* __restrict__ B,
             void* __restrict__ Cout, int M, int N, int K) {
    __shared__ __align__(16) bf16 ldsA[2][128 * 64];
    __shared__ __align__(16) bf16 ldsB[2][2][128 * 64];

    const int nN = N >> 8;
    const int cpx = gridDim.x >> 3;
    const int lin = (blockIdx.x & 7) * cpx + (blockIdx.x >> 3);  // XCD-chunked
    const int m0 = (lin / nN) * 128, n0 = (lin % nN) * 256;

    const int tid = threadIdx.x;
    const int w = tid >> 6, l = tid & 63;
    const int wm = w >> 2, wn = w & 3;
    const int lg = l >> 4, lc = l & 15;
    const int swz = (lc & 7) << 4;
    const int NT = K >> 6;

    f32x4 acc[2][4][2] = {};   // [nq][mt][nt]

    auto stageA = [&](int tau) {
        bf16* dst = &ldsA[tau & 1][0];
#pragma unroll
        for (int j = 0; j < 2; ++j) {
            int r = w * 16 + j * 8 + (l >> 3);
            int scb = ((l & 7) * 16) ^ ((r & 7) << 4);
            gld16(dst + (w * 16 + j * 8) * 64, A + (size_t)(m0 + r) * K + tau * 64 + (scb >> 1));
        }
    };
    auto stageB = [&](int tau, int u) {
        bf16* dst = &ldsB[tau & 1][u][0];
#pragma unroll
        for (int j = 0; j < 2; ++j) {
            int r = w * 16 + j * 8 + (l >> 3);
            int scb = ((l & 7) * 16) ^ ((r & 7) << 4);
            gld16(dst + (w * 16 + j * 8) * 64, B + (size_t)(n0 + u * 128 + r) * K + tau * 64 + (scb >> 1));
        }
    };

    // prologue: tile0 fully + A(1); tile0 resident, A(1) in flight
    stageA(0); stageB(0, 0); stageB(0, 1); stageA(1);
    SBAR();
    asm volatile("s_waitcnt vmcnt(2)" ::: "memory");
    HWBAR();

    for (int t = 0; t < NT; ++t) {
        const int c = t & 1;
        const char* Ab = (const char*)&ldsA[c][0];
        const char* Bb = (const char*)&ldsB[c][wn >> 1][0];
        const int brow0 = (wn & 1) * 64;
        bf16x8 Af[4][2], Bf[2][2];

        // ---- phase 0 (nq0): read A + B(nq0); stage B0(t+1) ----
#pragma unroll
        for (int mt = 0; mt < 4; ++mt)
#pragma unroll
            for (int ks = 0; ks < 2; ++ks)
                Af[mt][ks] = *(const bf16x8*)(Ab + (wm * 64 + mt * 16 + lc) * 128 + ((ks * 64 + lg * 16) ^ swz));
#pragma unroll
        for (int nt = 0; nt < 2; ++nt)
#pragma unroll
            for (int ks = 0; ks < 2; ++ks)
                Bf[nt][ks] = *(const bf16x8*)(Bb + (brow0 + nt * 16 + lc) * 128 + ((ks * 64 + lg * 16) ^ swz));
        if (t + 1 < NT) stageB(t + 1, 0);
        HWBAR();
        __builtin_amdgcn_s_setprio(1);
#pragma unroll
        for (int mt = 0; mt < 4; ++mt)
#pragma unroll
            for (int nt = 0; nt < 2; ++nt)
#pragma unroll
                for (int ks = 0; ks < 2; ++ks)
                    acc[0][mt][nt] = __builtin_amdgcn_mfma_f32_16x16x32_bf16(Af[mt][ks], Bf[nt][ks], acc[0][mt][nt], 0, 0, 0);
        __builtin_amdgcn_s_setprio(0);
        HWBAR();

        // ---- phase 1 (nq1): read B(nq1); stage B1(t+1) + A(t+2) ----
#pragma unroll
        for (int nt = 0; nt < 2; ++nt)
#pragma unroll
            for (int ks = 0; ks < 2; ++ks)
                Bf[nt][ks] = *(const bf16x8*)(Bb + (brow0 + 32 + nt * 16 + lc) * 128 + ((ks * 64 + lg * 16) ^ swz));
        if (t + 1 < NT) stageB(t + 1, 1);
        if (t + 2 < NT) stageA(t + 2);
        HWBAR();
        __builtin_amdgcn_s_setprio(1);
#pragma unroll
        for (int mt = 0; mt < 4; ++mt)
#pragma unroll
            for (int nt = 0; nt < 2; ++nt)
#pragma unroll
                for (int ks = 0; ks < 2; ++ks)
                    acc[1][mt][nt] = __builtin_amdgcn_mfma_f32_16x16x32_bf16(Af[mt][ks], Bf[nt][ks], acc[1][mt][nt], 0, 0, 0);
        __builtin_amdgcn_s_setprio(0);
        SBAR();
        if (t + 2 < NT) asm volatile("s_waitcnt vmcnt(2)" ::: "memory");
        else            asm volatile("s_waitcnt vmcnt(0)" ::: "memory");
        HWBAR();
    }

    // ---- epilogue ----
#pragma unroll
    for (int nq = 0; nq < 2; ++nq)
#pragma unroll
        for (int mt = 0; mt < 4; ++mt)
#pragma unroll
            for (int nt = 0; nt < 2; ++nt)
#pragma unroll
                for (int rr = 0; rr < 4; ++rr) {
                    size_t row = (size_t)m0 + wm * 64 + mt * 16 + lg * 4 + rr;
                    size_t col = (size_t)n0 + wn * 64 + nq * 32 + nt * 16 + lc;
                    float v = acc[nq][mt][nt][rr];
                    if (OUTF32) ((float*)Cout)[row * N + col] = v;
                    else        ((bf16*)Cout)[row * N + col] = (bf16)v;
                }
}

// ---------------- Flash attention: QBLK=128, 1 tile/block, 2 blocks/CU ----------
// 512 blocks; bid and bid+256 share a CU -> complementary tiles qt+qt'=15.
// Per XCD: 4 heads (K/V working set ~4 MB = L2). Big tiles dispatch first.
__global__ __launch_bounds__(512)
void flash_attn(const bf16* __restrict__ QKV, const bf16* __restrict__ Vt,
                bf16* __restrict__ O) {
    __shared__ __align__(16) bf16 Ks[2][64 * 128];   // [key][d], rows 256B (32 KB)
    __shared__ __align__(16) bf16 Vs[2][128 * 64];   // [d][key], rows 128B (32 KB)
    __shared__ __align__(16) bf16 p_lds[8][16 * 64]; // per-wave P[q][key] (16 KB)

    const int bid = blockIdx.x;                   // 512
    const int xcd = bid & 7, loc = bid >> 3;      // loc 0..63
    const int bh = (xcd << 2) + (loc & 3);        // 4 heads per XCD
    const int jjj = loc >> 2;                     // 0..15
    const int qt = (jjj < 8) ? (15 - jjj) : (jjj - 8);  // complementary pairing
    const int b = bh >> 4, h = bh & 15;

    const int tid = threadIdx.x;
    const int w = tid >> 6, l = tid & 63;         // w 0..7
    const int lg = l >> 4, lc = l & 15;
    const int kswz = (lc & 7) << 4;
    char* pb = (char*)&p_lds[w][0];

    auto stageK = [&](int p, int kb) {
#pragma unroll
        for (int c = 0; c < 2; ++c) {
            int r = c * 32 + w * 4 + (l >> 4);
            int scb = ((l & 15) * 16) ^ ((r & 7) << 4);
            const bf16* g = QKV + ((size_t)(b * SEQ + kb * 64 + r)) * QKV_LD + D_MODEL + h * HD + (scb >> 1);
            gld16(&Ks[p][(c * 32 + w * 4) * 128], g);
        }
    };
    auto stageV = [&](int p, int kb) {
#pragma unroll
        for (int c = 0; c < 2; ++c) {
            int r = c * 64 + w * 8 + (l >> 3);
            int scb = ((l & 7) * 16) ^ ((r & 7) << 4);
            const bf16* g = Vt + ((size_t)bh * HD + r) * SEQ + kb * 64 + (scb >> 1);
            gld16(&Vs[p][(c * 64 + w * 8) * 64], g);
        }
    };

    const int q0 = qt * 128 + w * 16;
    const int kbmax = 2 * qt + 1;                 // last key block index

    const bf16* qp = QKV + ((size_t)(b * SEQ + q0 + lc)) * QKV_LD + h * HD + lg * 8;
    bf16x8 qf[4];
#pragma unroll
    for (int kc = 0; kc < 4; ++kc) qf[kc] = *(const bf16x8*)(qp + kc * 32);

    f32x4 ctx[8] = {};
    float m_s = -INFINITY, l_s = 0.f;

    int cur = 0;
    stageK(cur, 0);
    stageV(cur, 0);

    for (int kb = 0; kb <= kbmax; ++kb) {
        __syncthreads();
        if (kb < kbmax) { stageK(cur ^ 1, kb + 1); stageV(cur ^ 1, kb + 1); }

        const char* kbp = (const char*)&Ks[cur][0];
        f32x4 st[4] = {};
#pragma unroll
        for (int nf = 0; nf < 4; ++nf) {
            int krow = nf * 16 + lc;
#pragma unroll
            for (int kc = 0; kc < 4; ++kc) {
                bf16x8 kf = *(const bf16x8*)(kbp + krow * 256 + ((kc * 64 + lg * 16) ^ kswz));
                st[nf] = __builtin_amdgcn_mfma_f32_16x16x32_bf16(kf, qf[kc], st[nf], 0, 0, 0);
            }
        }

        if (kb >= 2 * qt) {  // diagonal region: mask key > q
            int q = q0 + lc;
#pragma unroll
            for (int nf = 0; nf < 4; ++nf) {
                int key = kb * 64 + nf * 16 + lg * 4;
#pragma unroll
                for (int r = 0; r < 4; ++r)
                    if (key + r > q) st[nf][r] = -INFINITY;
            }
        }

        // row max: in-lane tree + 2 shfl stages
        float m01 = fmaxf(fmaxf(st[0][0], st[0][1]), fmaxf(st[0][2], st[0][3]));
        float m23 = fmaxf(fmaxf(st[1][0], st[1][1]), fmaxf(st[1][2], st[1][3]));
        float m45 = fmaxf(fmaxf(st[2][0], st[2][1]), fmaxf(st[2][2], st[2][3]));
        float m67 = fmaxf(fmaxf(st[3][0], st[3][1]), fmaxf(st[3][2], st[3][3]));
        float mx = fmaxf(fmaxf(m01, m23), fmaxf(m45, m67));
        mx = fmaxf(mx, __shfl_xor(mx, 16));
        mx = fmaxf(mx, __shfl_xor(mx, 32));

        // T13 defer-max: skip rescale while max growth <= 8 (P bounded by e^8)
        bool defer = __all(mx <= m_s + 8.f) && (m_s > -INFINITY);
        float mi;
        if (defer) {
            mi = m_s;
        } else {
            mi = fmaxf(m_s, mx);
            float scv = __expf(m_s - mi);
            float scvr[4];
#pragma unroll
            for (int r = 0; r < 4; ++r) scvr[r] = __shfl(scv, lg * 4 + r);
#pragma unroll
            for (int nd = 0; nd < 8; ++nd)
#pragma unroll
                for (int r = 0; r < 4; ++r) ctx[nd][r] *= scvr[r];
            l_s *= scv;
            m_s = mi;
        }

        float rs = 0.f;
#pragma unroll
        for (int nf = 0; nf < 4; ++nf) {
            float p0 = __expf(st[nf][0] - mi);
            float p1 = __expf(st[nf][1] - mi);
            float p2 = __expf(st[nf][2] - mi);
            float p3 = __expf(st[nf][3] - mi);
            rs += (p0 + p1) + (p2 + p3);
            bf16x4 pv = { (bf16)p0, (bf16)p1, (bf16)p2, (bf16)p3 };
            *(bf16x4*)(pb + lc * 128 + ((nf * 32 + lg * 8) ^ kswz)) = pv;
        }
        rs += __shfl_xor(rs, 16);
        rs += __shfl_xor(rs, 32);
        l_s += rs;

        asm volatile("s_waitcnt lgkmcnt(0)" ::: "memory");
        SBAR();
        bf16x8 pa0 = *(const bf16x8*)(pb + lc * 128 + ((lg * 16) ^ kswz));
        bf16x8 pa1 = *(const bf16x8*)(pb + lc * 128 + ((64 + lg * 16) ^ kswz));

        const char* vb = (const char*)&Vs[cur][0];
#pragma unroll
        for (int nd = 0; nd < 8; ++nd) {
            int vrow = nd * 16 + lc;
#pragma unroll
            for (int k2 = 0; k2 < 2; ++k2) {
                bf16x8 vf = *(const bf16x8*)(vb + vrow * 128 + ((k2 * 64 + lg * 16) ^ kswz));
                ctx[nd] = __builtin_amdgcn_mfma_f32_16x16x32_bf16(k2 ? pa1 : pa0, vf, ctx[nd], 0, 0, 0);
            }
        }
        cur ^= 1;
    }

    float lr[4];
#pragma unroll
    for (int r = 0; r < 4; ++r) lr[r] = 1.f / __shfl(l_s, lg * 4 + r);
#pragma unroll
    for (int nd = 0; nd < 8; ++nd)
#pragma unroll
        for (int r = 0; r < 4; ++r)
            O[((size_t)(b * SEQ + q0 + lg * 4 + r)) * D_MODEL + h * HD + nd * 16 + lc] =
                (bf16)(ctx[nd][r] * lr[r]);
}

// ---------------- launch ----------------
extern "C" void kernel_launch(void* const* d_in, const int* in_sizes, int n_in,
                              void* d_out, int out_size, void* d_ws, size_t ws_size,
                              hipStream_t stream) {
    const float* x  = (const float*)d_in[0];
    const float* Wq = (const float*)d_in[1];
    const float* Wk = (const float*)d_in[2];
    const float* Wv = (const float*)d_in[3];
    const float* Wo = (const float*)d_in[4];

    char* ws = (char*)d_ws;
    bf16* xb   = (bf16*)(ws + 0);            // 16 MB; reused as ctx after QKV GEMM
    bf16* wqkv = (bf16*)(ws + 16777216);     // 24 MB  [6144][2048]
    bf16* wob  = (bf16*)(ws + 41943040);     // 8 MB
    bf16* QKV  = (bf16*)(ws + 50331648);     // 48 MB  [4096][6144]
    bf16* Vtb  = (bf16*)(ws + 100663296);    // 16 MB  [B,H,D,S]
    float* cosd = (float*)(ws + 117440512);
    float* sind = (float*)(ws + 117964800);

    // fused convert: 25165824 elems -> contiguous xb|wqkv|wob
    cvt_all<<<25165824 / 1024, 256, 0, stream>>>(x, Wq, Wk, Wv, Wo, xb);

    rope_tables_k<<<(SEQ * 64) / 256, 256, 0, stream>>>(cosd, sind);

    // fused QKV projection: [4096,2048] x [6144,2048]^T -> [4096,6144]
    gemm128<0><<<dim3(768), 512, 0, stream>>>(
        xb, wqkv, QKV, BATCH * SEQ, QKV_LD, D_MODEL);

    const float qscale = 0.08838834764831845f;  // 1/sqrt(128)
    rope_apply2<<<(2 * BATCH * SEQ * 1024) / 256, 256, 0, stream>>>(QKV, cosd, sind, qscale);

    transpose_v<<<dim3(SEQ / 32, HD / 32, BATCH * NH), 256, 0, stream>>>(QKV + 2 * D_MODEL, Vtb, QKV_LD);

    flash_attn<<<dim3(512), 512, 0, stream>>>(QKV, Vtb, xb /*ctx*/);

    // output projection: [4096,2048] x [2048,2048]^T -> d_out (f32)
    gemm128<1><<<dim3(256), 512, 0, stream>>>(
        xb, wob, d_out, BATCH * SEQ, D_MODEL, D_MODEL);
}

// Round 18
// 267.721 us; speedup vs baseline: 1.0648x; 1.0051x over previous
//
#include <hip/hip_runtime.h>
#include <hip/hip_bf16.h>
#include <cstdint>
#include <cstddef>

typedef __bf16 bf16;
typedef __bf16 bf16x4 __attribute__((ext_vector_type(4)));
typedef __bf16 bf16x8 __attribute__((ext_vector_type(8)));
typedef float f32x4 __attribute__((ext_vector_type(4)));

#define D_MODEL 2048
#define SEQ     2048
#define NH      16
#define HD      128
#define BATCH   2
#define QKV_LD  6144

#define SBAR()  __builtin_amdgcn_sched_barrier(0)
#define HWBAR() do { SBAR(); __builtin_amdgcn_s_barrier(); SBAR(); } while (0)

// ---------------- async global->LDS 16B ----------------
__device__ __forceinline__ void gld16(void* lds, const void* g) {
    __builtin_amdgcn_global_load_lds(
        (const __attribute__((address_space(1))) unsigned int*)g,
        (__attribute__((address_space(3))) unsigned int*)lds,
        16, 0, 0);
}

// ---------------- fused fp32 -> bf16 convert (x, Wq, Wk, Wv, Wo) ----------------
__global__ __launch_bounds__(256) void cvt_all(const float* __restrict__ x,
                                               const float* __restrict__ Wq,
                                               const float* __restrict__ Wk,
                                               const float* __restrict__ Wv,
                                               const float* __restrict__ Wo,
                                               bf16* __restrict__ out) {
    int i = (blockIdx.x * 256 + threadIdx.x) * 4;  // 25165824 total elems
    const float* src;
    int off;
    if (i < 8388608) { src = x; off = i; }
    else {
        int j = i - 8388608;
        int seg = j >> 22;
        src = (seg == 0) ? Wq : (seg == 1) ? Wk : (seg == 2) ? Wv : Wo;
        off = j & 4194303;
    }
    float4 v = *(const float4*)(src + off);
    bf16* o = out + i;
    o[0] = (bf16)v.x; o[1] = (bf16)v.y; o[2] = (bf16)v.z; o[3] = (bf16)v.w;
}

// ---------------- RoPE tables (cos/sin, S x 64) ----------------
__global__ __launch_bounds__(256) void rope_tables_k(float* __restrict__ cosd,
                                                     float* __restrict__ sind) {
    int id = blockIdx.x * 256 + threadIdx.x;  // SEQ*64
    int s = id >> 6, d = id & 63;
    float freq = powf(10000.f, -(float)d * (1.f / 64.f));
    float a = (float)s * freq;
    float sn, c;
    sincosf(a, &sn, &c);
    cosd[id] = c;
    sind[id] = sn;
}

// ---------------- RoPE apply, Q and K regions in one launch ----------------
// total threads = 2 * B*S*NH*64 = 2^23; per-half = 2^22.
__global__ __launch_bounds__(256) void rope_apply2(bf16* __restrict__ T,
                                                   const float* __restrict__ cosd,
                                                   const float* __restrict__ sind,
                                                   float qscale) {
    int id = blockIdx.x * 256 + threadIdx.x;
    int half = id >> 22;                       // 0 = Q, 1 = K
    int jd = id & 4194303;                     // 2^22 - 1
    int row = jd >> 10;                        // B*S
    int p = jd & 1023;
    int h = p >> 6, d = p & 63;
    int s = row & (SEQ - 1);
    size_t base = (size_t)row * QKV_LD + half * D_MODEL + h * HD + d;
    float scale = half ? 1.0f : qscale;
    float x1 = (float)T[base];
    float x2 = (float)T[base + 64];
    float c = cosd[(s << 6) + d];
    float sn = sind[(s << 6) + d];
    T[base]      = (bf16)((x1 * c - x2 * sn) * scale);
    T[base + 64] = (bf16)((x2 * c + x1 * sn) * scale);
}

// ---------------- V transpose: [B,S,(ld)] head cols -> [B,H,D,S] ----------------
__global__ __launch_bounds__(256) void transpose_v(const bf16* __restrict__ V,
                                                   bf16* __restrict__ Vt, int ld) {
    __shared__ bf16 t[32][33];
    int s0 = blockIdx.x * 32;
    int d0 = blockIdx.y * 32;
    int bh = blockIdx.z;
    int b = bh >> 4, h = bh & 15;
    int tx = threadIdx.x & 31, ty = threadIdx.x >> 5;  // ty 0..7
#pragma unroll
    for (int i = 0; i < 32; i += 8)
        t[ty + i][tx] = V[((size_t)(b * SEQ + s0 + ty + i)) * ld + h * HD + d0 + tx];
    __syncthreads();
#pragma unroll
    for (int i = 0; i < 32; i += 8)
        Vt[((size_t)bh * HD + d0 + ty + i) * SEQ + s0 + tx] = t[tx][ty + i];
}

// ---------------- 256x256 NT GEMM, faithful 8-phase (m201-style) ----------------
// 512 thr = 8 waves (2m x 4n), per-wave C 128x64. BK=64, LDS 128 KB dbuf.
// Per tile: 4 phases {ds-read quadrant, stage ONE half-tile, bar, lgkmcnt(0),
// setprio(1), 16 MFMA, setprio(0), bar}. Stage stream (region-derived):
//   ph0: B1(t+1)  ph1: A1(t+1)  ph2: B0(t+2)  ph3: A0(t+2)
// Boundary: vmcnt(4) (only the two t+2 stages stay in flight, 5-6 phases deep).
template <int OUTF32>
__global__ __launch_bounds__(512, 2)
void gemm256(const bf16* __restrict__ A, const bf16* __restrict__ B,
             void* __restrict__ Cout, int M, int N, int K) {
    __shared__ __align__(16) bf16 lds[2][2][2][128 * 64];  // [buf][A/B][unit][.]

    const int nN = N >> 8;
    const int cpx = gridDim.x >> 3;
    const int lin = (blockIdx.x & 7) * cpx + (blockIdx.x >> 3);  // XCD-chunked
    const int m0 = (lin / nN) * 256, n0 = (lin % nN) * 256;

    const int tid = threadIdx.x;
    const int w = tid >> 6, l = tid & 63;
    const int wm = w >> 2, wn = w & 3;
    const int lg = l >> 4, lc = l & 15;
    const int swz = (lc & 7) << 4;
    const int NT = K >> 6;

    f32x4 acc[2][2][4][2] = {};   // [mq][nq][mt][nt]

    // stage one half-tile (unit): ab 0=A 1=B; u row-half
    auto stage = [&](int tau, int ab, int u) {
        bf16* dst = &lds[tau & 1][ab][u][0];
        const bf16* src = (ab == 0) ? A + (size_t)(m0 + u * 128) * K
                                    : B + (size_t)(n0 + u * 128) * K;
#pragma unroll
        for (int j = 0; j < 2; ++j) {
            int r = w * 16 + j * 8 + (l >> 3);
            int scb = ((l & 7) * 16) ^ ((r & 7) << 4);
            gld16(dst + (w * 16 + j * 8) * 64, src + (size_t)r * K + tau * 64 + (scb >> 1));
        }
    };

    // prologue: tile0 all units + tile1 {B0, A0}; then tile0 resident
    stage(0, 0, 0); stage(0, 0, 1); stage(0, 1, 0); stage(0, 1, 1);
    stage(1, 1, 0); stage(1, 0, 0);
    SBAR();
    asm volatile("s_waitcnt vmcnt(4)" ::: "memory");
    HWBAR();

    for (int t = 0; t < NT; ++t) {
        const char* Ab = (const char*)&lds[t & 1][0][wm][0];
        const char* Bb = (const char*)&lds[t & 1][1][wn >> 1][0];
        const int brow0 = (wn & 1) * 64;
        bf16x8 Af[4][2], Bf[2][2][2];

        // ---- phase 0: quadrant (mq0, nq0); stage B1(t+1) ----
#pragma unroll
        for (int mt = 0; mt < 4; ++mt)
#pragma unroll
            for (int ks = 0; ks < 2; ++ks)
                Af[mt][ks] = *(const bf16x8*)(Ab + (mt * 16 + lc) * 128 + ((ks * 64 + lg * 16) ^ swz));
#pragma unroll
        for (int nt = 0; nt < 2; ++nt)
#pragma unroll
            for (int ks = 0; ks < 2; ++ks)
                Bf[0][nt][ks] = *(const bf16x8*)(Bb + (brow0 + nt * 16 + lc) * 128 + ((ks * 64 + lg * 16) ^ swz));
        if (t + 1 < NT) stage(t + 1, 1, 1);
        SBAR(); __builtin_amdgcn_s_barrier();
        asm volatile("s_waitcnt lgkmcnt(0)" ::: "memory"); SBAR();
        __builtin_amdgcn_s_setprio(1);
#pragma unroll
        for (int mt = 0; mt < 4; ++mt)
#pragma unroll
            for (int nt = 0; nt < 2; ++nt)
#pragma unroll
                for (int ks = 0; ks < 2; ++ks)
                    acc[0][0][mt][nt] = __builtin_amdgcn_mfma_f32_16x16x32_bf16(Af[mt][ks], Bf[0][nt][ks], acc[0][0][mt][nt], 0, 0, 0);
        __builtin_amdgcn_s_setprio(0);
        HWBAR();

        // ---- phase 1: quadrant (mq0, nq1); stage A1(t+1) ----
#pragma unroll
        for (int nt = 0; nt < 2; ++nt)
#pragma unroll
            for (int ks = 0; ks < 2; ++ks)
                Bf[1][nt][ks] = *(const bf16x8*)(Bb + (brow0 + 32 + nt * 16 + lc) * 128 + ((ks * 64 + lg * 16) ^ swz));
        if (t + 1 < NT) stage(t + 1, 0, 1);
        SBAR(); __builtin_amdgcn_s_barrier();
        asm volatile("s_waitcnt lgkmcnt(0)" ::: "memory"); SBAR();
        __builtin_amdgcn_s_setprio(1);
#pragma unroll
        for (int mt = 0; mt < 4; ++mt)
#pragma unroll
            for (int nt = 0; nt < 2; ++nt)
#pragma unroll
                for (int ks = 0; ks < 2; ++ks)
                    acc[0][1][mt][nt] = __builtin_amdgcn_mfma_f32_16x16x32_bf16(Af[mt][ks], Bf[1][nt][ks], acc[0][1][mt][nt], 0, 0, 0);
        __builtin_amdgcn_s_setprio(0);
        HWBAR();

        // ---- phase 2: quadrant (mq1, nq0); re-read A rows 64-127; stage B0(t+2) ----
#pragma unroll
        for (int mt = 0; mt < 4; ++mt)
#pragma unroll
            for (int ks = 0; ks < 2; ++ks)
                Af[mt][ks] = *(const bf16x8*)(Ab + (64 + mt * 16 + lc) * 128 + ((ks * 64 + lg * 16) ^ swz));
        if (t + 2 < NT) stage(t + 2, 1, 0);
        SBAR(); __builtin_amdgcn_s_barrier();
        asm volatile("s_waitcnt lgkmcnt(0)" ::: "memory"); SBAR();
        __builtin_amdgcn_s_setprio(1);
#pragma unroll
        for (int mt = 0; mt < 4; ++mt)
#pragma unroll
            for (int nt = 0; nt < 2; ++nt)
#pragma unroll
                for (int ks = 0; ks < 2; ++ks)
                    acc[1][0][mt][nt] = __builtin_amdgcn_mfma_f32_16x16x32_bf16(Af[mt][ks], Bf[0][nt][ks], acc[1][0][mt][nt], 0, 0, 0);
        __builtin_amdgcn_s_setprio(0);
        HWBAR();

        // ---- phase 3: quadrant (mq1, nq1); stage A0(t+2); boundary vmcnt ----
        if (t + 2 < NT) stage(t + 2, 0, 0);
        SBAR(); __builtin_amdgcn_s_barrier(); SBAR();
        __builtin_amdgcn_s_setprio(1);
#pragma unroll
        for (int mt = 0; mt < 4; ++mt)
#pragma unroll
            for (int nt = 0; nt < 2; ++nt)
#pragma unroll
                for (int ks = 0; ks < 2; ++ks)
                    acc[1][1][mt][nt] = __builtin_amdgcn_mfma_f32_16x16x32_bf16(Af[mt][ks], Bf[1][nt][ks], acc[1][1][mt][nt], 0, 0, 0);
        __builtin_amdgcn_s_setprio(0);
        SBAR();
        if (t + 2 < NT) asm volatile("s_waitcnt vmcnt(4)" ::: "memory");
        else            asm volatile("s_waitcnt vmcnt(0)" ::: "memory");
        __builtin_amdgcn_s_barrier(); SBAR();
    }

    // ---- epilogue ----
#pragma unroll
    for (int mq = 0; mq < 2; ++mq)
#pragma unroll
        for (int nq = 0; nq < 2; ++nq)
#pragma unroll
            for (int mt = 0; mt < 4; ++mt)
#pragma unroll
                for (int nt = 0; nt < 2; ++nt)
#pragma unroll
                    for (int rr = 0; rr < 4; ++rr) {
                        size_t row = (size_t)m0 + wm * 128 + mq * 64 + mt * 16 + lg * 4 + rr;
                        size_t col = (size_t)n0 + wn * 64 + nq * 32 + nt * 16 + lc;
                        float v = acc[mq][nq][mt][nt][rr];
                        if (OUTF32) ((float*)Cout)[row * N + col] = v;
                        else        ((bf16*)Cout)[row * N + col] = (bf16)v;
                    }
}

// ---------------- 128x256 NT GEMM, 2-phase pipelined (R11-exact, out-proj) ----
template <int OUTF32>
__global__ __launch_bounds__(512, 2)
void gemm128(const bf16* __restrict__ A, const bf16* __restrict__ B,
             void* __restrict__ Cout, int M, int N, int K) {
    __shared__ __align__(16) bf16 ldsA[2][128 * 64];
    __shared__ __align__(16) bf16 ldsB[2][2][128 * 64];

    const int nN = N >> 8;
    const int cpx = gridDim.x >> 3;
    const int lin = (blockIdx.x & 7) * cpx + (blockIdx.x >> 3);  // XCD-chunked
    const int m0 = (lin / nN) * 128, n0 = (lin % nN) * 256;

    const int tid = threadIdx.x;
    const int w = tid >> 6, l = tid & 63;
    const int wm = w >> 2, wn = w & 3;
    const int lg = l >> 4, lc = l & 15;
    const int swz = (lc & 7) << 4;
    const int NT = K >> 6;

    f32x4 acc[2][4][2] = {};   // [nq][mt][nt]

    auto stageA = [&](int tau) {
        bf16* dst = &ldsA[tau & 1][0];
#pragma unroll
        for (int j = 0; j < 2; ++j) {
            int r = w * 16 + j * 8 + (l >> 3);
            int scb = ((l & 7) * 16) ^ ((r & 7) << 4);
            gld16(dst + (w * 16 + j * 8) * 64, A + (size_t)(m0 + r) * K + tau * 64 + (scb >> 1));
        }
    };
    auto stageB = [&](int tau, int u) {
        bf16* dst = &ldsB[tau & 1][u][0];
#pragma unroll
        for (int j = 0; j < 2; ++j) {
            int r = w * 16 + j * 8 + (l >> 3);
            int scb = ((l & 7) * 16) ^ ((r & 7) << 4);
            gld16(dst + (w * 16 + j * 8) * 64, B + (size_t)(n0 + u * 128 + r) * K + tau * 64 + (scb >> 1));
        }
    };

    stageA(0); stageB(0, 0); stageB(0, 1); stageA(1);
    SBAR();
    asm volatile("s_waitcnt vmcnt(2)" ::: "memory");
    HWBAR();

    for (int t = 0; t < NT; ++t) {
        const int c = t & 1;
        const char* Ab = (const char*)&ldsA[c][0];
        const char* Bb = (const char*)&ldsB[c][wn >> 1][0];
        const int brow0 = (wn & 1) * 64;
        bf16x8 Af[4][2], Bf[2][2];

#pragma unroll
        for (int mt = 0; mt < 4; ++mt)
#pragma unroll
            for (int ks = 0; ks < 2; ++ks)
                Af[mt][ks] = *(const bf16x8*)(Ab + (wm * 64 + mt * 16 + lc) * 128 + ((ks * 64 + lg * 16) ^ swz));
#pragma unroll
        for (int nt = 0; nt < 2; ++nt)
#pragma unroll
            for (int ks = 0; ks < 2; ++ks)
                Bf[nt][ks] = *(const bf16x8*)(Bb + (brow0 + nt * 16 + lc) * 128 + ((ks * 64 + lg * 16) ^ swz));
        if (t + 1 < NT) stageB(t + 1, 0);
        HWBAR();
        __builtin_amdgcn_s_setprio(1);
#pragma unroll
        for (int mt = 0; mt < 4; ++mt)
#pragma unroll
            for (int nt = 0; nt < 2; ++nt)
#pragma unroll
                for (int ks = 0; ks < 2; ++ks)
                    acc[0][mt][nt] = __builtin_amdgcn_mfma_f32_16x16x32_bf16(Af[mt][ks], Bf[nt][ks], acc[0][mt][nt], 0, 0, 0);
        __builtin_amdgcn_s_setprio(0);
        HWBAR();

#pragma unroll
        for (int nt = 0; nt < 2; ++nt)
#pragma unroll
            for (int ks = 0; ks < 2; ++ks)
                Bf[nt][ks] = *(const bf16x8*)(Bb + (brow0 + 32 + nt * 16 + lc) * 128 + ((ks * 64 + lg * 16) ^ swz));
        if (t + 1 < NT) stageB(t + 1, 1);
        if (t + 2 < NT) stageA(t + 2);
        HWBAR();
        __builtin_amdgcn_s_setprio(1);
#pragma unroll
        for (int mt = 0; mt < 4; ++mt)
#pragma unroll
            for (int nt = 0; nt < 2; ++nt)
#pragma unroll
                for (int ks = 0; ks < 2; ++ks)
                    acc[1][mt][nt] = __builtin_amdgcn_mfma_f32_16x16x32_bf16(Af[mt][ks], Bf[nt][ks], acc[1][mt][nt], 0, 0, 0);
        __builtin_amdgcn_s_setprio(0);
        SBAR();
        if (t + 2 < NT) asm volatile("s_waitcnt vmcnt(2)" ::: "memory");
        else            asm volatile("s_waitcnt vmcnt(0)" ::: "memory");
        HWBAR();
    }

#pragma unroll
    for (int nq = 0; nq < 2; ++nq)
#pragma unroll
        for (int mt = 0; mt < 4; ++mt)
#pragma unroll
            for (int nt = 0; nt < 2; ++nt)
#pragma unroll
                for (int rr = 0; rr < 4; ++rr) {
                    size_t row = (size_t)m0 + wm * 64 + mt * 16 + lg * 4 + rr;
                    size_t col = (size_t)n0 + wn * 64 + nq * 32 + nt * 16 + lc;
                    float v = acc[nq][mt][nt][rr];
                    if (OUTF32) ((float*)Cout)[row * N + col] = v;
                    else        ((bf16*)Cout)[row * N + col] = (bf16)v;
                }
}

// ---------------- Flash attention (R17-exact) ----------------
__global__ __launch_bounds__(512)
void flash_attn(const bf16* __restrict__ QKV, const bf16* __restrict__ Vt,
                bf16* __restrict__ O) {
    __shared__ __align__(16) bf16 Ks[2][64 * 128];   // [key][d], rows 256B (32 KB)
    __shared__ __align__(16) bf16 Vs[2][128 * 64];   // [d][key], rows 128B (32 KB)
    __shared__ __align__(16) bf16 p_lds[8][16 * 64]; // per-wave P[q][key] (16 KB)

    const int bid = blockIdx.x;                   // 512
    const int xcd = bid & 7, loc = bid >> 3;      // loc 0..63
    const int bh = (xcd << 2) + (loc & 3);        // 4 heads per XCD
    const int jjj = loc >> 2;                     // 0..15
    const int qt = (jjj < 8) ? (15 - jjj) : (jjj - 8);  // complementary pairing
    const int b = bh >> 4, h = bh & 15;

    const int tid = threadIdx.x;
    const int w = tid >> 6, l = tid & 63;         // w 0..7
    const int lg = l >> 4, lc = l & 15;
    const int kswz = (lc & 7) << 4;
    char* pb = (char*)&p_lds[w][0];

    auto stageK = [&](int p, int kb) {
#pragma unroll
        for (int c = 0; c < 2; ++c) {
            int r = c * 32 + w * 4 + (l >> 4);
            int scb = ((l & 15) * 16) ^ ((r & 7) << 4);
            const bf16* g = QKV + ((size_t)(b * SEQ + kb * 64 + r)) * QKV_LD + D_MODEL + h * HD + (scb >> 1);
            gld16(&Ks[p][(c * 32 + w * 4) * 128], g);
        }
    };
    auto stageV = [&](int p, int kb) {
#pragma unroll
        for (int c = 0; c < 2; ++c) {
            int r = c * 64 + w * 8 + (l >> 3);
            int scb = ((l & 7) * 16) ^ ((r & 7) << 4);
            const bf16* g = Vt + ((size_t)bh * HD + r) * SEQ + kb * 64 + (scb >> 1);
            gld16(&Vs[p][(c * 64 + w * 8) * 64], g);
        }
    };

    const int q0 = qt * 128 + w * 16;
    const int kbmax = 2 * qt + 1;                 // last key block index

    const bf16* qp = QKV + ((size_t)(b * SEQ + q0 + lc)) * QKV_LD + h * HD + lg * 8;
    bf16x8 qf[4];
#pragma unroll
    for (int kc = 0; kc < 4; ++kc) qf[kc] = *(const bf16x8*)(qp + kc * 32);

    f32x4 ctx[8] = {};
    float m_s = -INFINITY, l_s = 0.f;

    int cur = 0;
    stageK(cur, 0);
    stageV(cur, 0);

    for (int kb = 0; kb <= kbmax; ++kb) {
        __syncthreads();
        if (kb < kbmax) { stageK(cur ^ 1, kb + 1); stageV(cur ^ 1, kb + 1); }

        const char* kbp = (const char*)&Ks[cur][0];
        f32x4 st[4] = {};
#pragma unroll
        for (int nf = 0; nf < 4; ++nf) {
            int krow = nf * 16 + lc;
#pragma unroll
            for (int kc = 0; kc < 4; ++kc) {
                bf16x8 kf = *(const bf16x8*)(kbp + krow * 256 + ((kc * 64 + lg * 16) ^ kswz));
                st[nf] = __builtin_amdgcn_mfma_f32_16x16x32_bf16(kf, qf[kc], st[nf], 0, 0, 0);
            }
        }

        if (kb >= 2 * qt) {  // diagonal region: mask key > q
            int q = q0 + lc;
#pragma unroll
            for (int nf = 0; nf < 4; ++nf) {
                int key = kb * 64 + nf * 16 + lg * 4;
#pragma unroll
                for (int r = 0; r < 4; ++r)
                    if (key + r > q) st[nf][r] = -INFINITY;
            }
        }

        // row max: in-lane tree + 2 shfl stages
        float m01 = fmaxf(fmaxf(st[0][0], st[0][1]), fmaxf(st[0][2], st[0][3]));
        float m23 = fmaxf(fmaxf(st[1][0], st[1][1]), fmaxf(st[1][2], st[1][3]));
        float m45 = fmaxf(fmaxf(st[2][0], st[2][1]), fmaxf(st[2][2], st[2][3]));
        float m67 = fmaxf(fmaxf(st[3][0], st[3][1]), fmaxf(st[3][2], st[3][3]));
        float mx = fmaxf(fmaxf(m01, m23), fmaxf(m45, m67));
        mx = fmaxf(mx, __shfl_xor(mx, 16));
        mx = fmaxf(mx, __shfl_xor(mx, 32));

        // T13 defer-max: skip rescale while max growth <= 8 (P bounded by e^8)
        bool defer = __all(mx <= m_s + 8.f) && (m_s > -INFINITY);
        float mi;
        if (defer) {
            mi = m_s;
        } else {
            mi = fmaxf(m_s, mx);
            float scv = __expf(m_s - mi);
            float scvr[4];
#pragma unroll
            for (int r = 0; r < 4; ++r) scvr[r] = __shfl(scv, lg * 4 + r);
#pragma unroll
            for (int nd = 0; nd < 8; ++nd)
#pragma unroll
                for (int r = 0; r < 4; ++r) ctx[nd][r] *= scvr[r];
            l_s *= scv;
            m_s = mi;
        }

        float rs = 0.f;
#pragma unroll
        for (int nf = 0; nf < 4; ++nf) {
            float p0 = __expf(st[nf][0] - mi);
            float p1 = __expf(st[nf][1] - mi);
            float p2 = __expf(st[nf][2] - mi);
            float p3 = __expf(st[nf][3] - mi);
            rs += (p0 + p1) + (p2 + p3);
            bf16x4 pv = { (bf16)p0, (bf16)p1, (bf16)p2, (bf16)p3 };
            *(bf16x4*)(pb + lc * 128 + ((nf * 32 + lg * 8) ^ kswz)) = pv;
        }
        rs += __shfl_xor(rs, 16);
        rs += __shfl_xor(rs, 32);
        l_s += rs;

        asm volatile("s_waitcnt lgkmcnt(0)" ::: "memory");
        SBAR();
        bf16x8 pa0 = *(const bf16x8*)(pb + lc * 128 + ((lg * 16) ^ kswz));
        bf16x8 pa1 = *(const bf16x8*)(pb + lc * 128 + ((64 + lg * 16) ^ kswz));

        const char* vb = (const char*)&Vs[cur][0];
#pragma unroll
        for (int nd = 0; nd < 8; ++nd) {
            int vrow = nd * 16 + lc;
#pragma unroll
            for (int k2 = 0; k2 < 2; ++k2) {
                bf16x8 vf = *(const bf16x8*)(vb + vrow * 128 + ((k2 * 64 + lg * 16) ^ kswz));
                ctx[nd] = __builtin_amdgcn_mfma_f32_16x16x32_bf16(k2 ? pa1 : pa0, vf, ctx[nd], 0, 0, 0);
            }
        }
        cur ^= 1;
    }

    float lr[4];
#pragma unroll
    for (int r = 0; r < 4; ++r) lr[r] = 1.f / __shfl(l_s, lg * 4 + r);
#pragma unroll
    for (int nd = 0; nd < 8; ++nd)
#pragma unroll
        for (int r = 0; r < 4; ++r)
            O[((size_t)(b * SEQ + q0 + lg * 4 + r)) * D_MODEL + h * HD + nd * 16 + lc] =
                (bf16)(ctx[nd][r] * lr[r]);
}

// ---------------- launch ----------------
extern "C" void kernel_launch(void* const* d_in, const int* in_sizes, int n_in,
                              void* d_out, int out_size, void* d_ws, size_t ws_size,
                              hipStream_t stream) {
    const float* x  = (const float*)d_in[0];
    const float* Wq = (const float*)d_in[1];
    const float* Wk = (const float*)d_in[2];
    const float* Wv = (const float*)d_in[3];
    const float* Wo = (const float*)d_in[4];

    char* ws = (char*)d_ws;
    bf16* xb   = (bf16*)(ws + 0);            // 16 MB; reused as ctx after QKV GEMM
    bf16* wqkv = (bf16*)(ws + 16777216);     // 24 MB  [6144][2048]
    bf16* wob  = (bf16*)(ws + 41943040);     // 8 MB
    bf16* QKV  = (bf16*)(ws + 50331648);     // 48 MB  [4096][6144]
    bf16* Vtb  = (bf16*)(ws + 100663296);    // 16 MB  [B,H,D,S]
    float* cosd = (float*)(ws + 117440512);
    float* sind = (float*)(ws + 117964800);

    // fused convert: 25165824 elems -> contiguous xb|wqkv|wob
    cvt_all<<<25165824 / 1024, 256, 0, stream>>>(x, Wq, Wk, Wv, Wo, xb);

    rope_tables_k<<<(SEQ * 64) / 256, 256, 0, stream>>>(cosd, sind);

    // fused QKV projection: [4096,2048] x [6144,2048]^T -> [4096,6144]
    // 256x256 tiles: 16x24 = 384 blocks, faithful 8-phase schedule
    gemm256<0><<<dim3(384), 512, 0, stream>>>(
        xb, wqkv, QKV, BATCH * SEQ, QKV_LD, D_MODEL);

    const float qscale = 0.08838834764831845f;  // 1/sqrt(128)
    rope_apply2<<<(2 * BATCH * SEQ * 1024) / 256, 256, 0, stream>>>(QKV, cosd, sind, qscale);

    transpose_v<<<dim3(SEQ / 32, HD / 32, BATCH * NH), 256, 0, stream>>>(QKV + 2 * D_MODEL, Vtb, QKV_LD);

    flash_attn<<<dim3(512), 512, 0, stream>>>(QKV, Vtb, xb /*ctx*/);

    // output projection: [4096,2048] x [2048,2048]^T -> d_out (f32)
    gemm128<1><<<dim3(256), 512, 0, stream>>>(
        xb, wob, d_out, BATCH * SEQ, D_MODEL, D_MODEL);
}

// Round 19
// 253.414 us; speedup vs baseline: 1.1250x; 1.0565x over previous
//
#include <hip/hip_runtime.h>
#include <hip/hip_bf16.h>
#include <cstdint>
#include <cstddef>

typedef __bf16 bf16;
typedef __bf16 bf16x4 __attribute__((ext_vector_type(4)));
typedef __bf16 bf16x8 __attribute__((ext_vector_type(8)));
typedef float f32x4 __attribute__((ext_vector_type(4)));

#define D_MODEL 2048
#define SEQ     2048
#define NH      16
#define HD      128
#define BATCH   2
#define QKV_LD  6144

#define SBAR()  __builtin_amdgcn_sched_barrier(0)
#define HWBAR() do { SBAR(); __builtin_amdgcn_s_barrier(); SBAR(); } while (0)

// ---------------- async global->LDS 16B ----------------
__device__ __forceinline__ void gld16(void* lds, const void* g) {
    __builtin_amdgcn_global_load_lds(
        (const __attribute__((address_space(1))) unsigned int*)g,
        (__attribute__((address_space(3))) unsigned int*)lds,
        16, 0, 0);
}

// ---------------- fused fp32 -> bf16 convert (x, Wq, Wk, Wv, Wo) ----------------
__global__ __launch_bounds__(256) void cvt_all(const float* __restrict__ x,
                                               const float* __restrict__ Wq,
                                               const float* __restrict__ Wk,
                                               const float* __restrict__ Wv,
                                               const float* __restrict__ Wo,
                                               bf16* __restrict__ out) {
    int i = (blockIdx.x * 256 + threadIdx.x) * 4;  // 25165824 total elems
    const float* src;
    int off;
    if (i < 8388608) { src = x; off = i; }
    else {
        int j = i - 8388608;
        int seg = j >> 22;
        src = (seg == 0) ? Wq : (seg == 1) ? Wk : (seg == 2) ? Wv : Wo;
        off = j & 4194303;
    }
    float4 v = *(const float4*)(src + off);
    bf16* o = out + i;
    o[0] = (bf16)v.x; o[1] = (bf16)v.y; o[2] = (bf16)v.z; o[3] = (bf16)v.w;
}

// ---------------- RoPE tables (cos/sin, S x 64) ----------------
__global__ __launch_bounds__(256) void rope_tables_k(float* __restrict__ cosd,
                                                     float* __restrict__ sind) {
    int id = blockIdx.x * 256 + threadIdx.x;  // SEQ*64
    int s = id >> 6, d = id & 63;
    float freq = powf(10000.f, -(float)d * (1.f / 64.f));
    float a = (float)s * freq;
    float sn, c;
    sincosf(a, &sn, &c);
    cosd[id] = c;
    sind[id] = sn;
}

// ---------------- RoPE apply, Q and K regions in one launch ----------------
// total threads = 2 * B*S*NH*64 = 2^23; per-half = 2^22.
__global__ __launch_bounds__(256) void rope_apply2(bf16* __restrict__ T,
                                                   const float* __restrict__ cosd,
                                                   const float* __restrict__ sind,
                                                   float qscale) {
    int id = blockIdx.x * 256 + threadIdx.x;
    int half = id >> 22;                       // 0 = Q, 1 = K
    int jd = id & 4194303;                     // 2^22 - 1
    int row = jd >> 10;                        // B*S
    int p = jd & 1023;
    int h = p >> 6, d = p & 63;
    int s = row & (SEQ - 1);
    size_t base = (size_t)row * QKV_LD + half * D_MODEL + h * HD + d;
    float scale = half ? 1.0f : qscale;
    float x1 = (float)T[base];
    float x2 = (float)T[base + 64];
    float c = cosd[(s << 6) + d];
    float sn = sind[(s << 6) + d];
    T[base]      = (bf16)((x1 * c - x2 * sn) * scale);
    T[base + 64] = (bf16)((x2 * c + x1 * sn) * scale);
}

// ---------------- V transpose: [B,S,(ld)] head cols -> [B,H,D,S] ----------------
__global__ __launch_bounds__(256) void transpose_v(const bf16* __restrict__ V,
                                                   bf16* __restrict__ Vt, int ld) {
    __shared__ bf16 t[32][33];
    int s0 = blockIdx.x * 32;
    int d0 = blockIdx.y * 32;
    int bh = blockIdx.z;
    int b = bh >> 4, h = bh & 15;
    int tx = threadIdx.x & 31, ty = threadIdx.x >> 5;  // ty 0..7
#pragma unroll
    for (int i = 0; i < 32; i += 8)
        t[ty + i][tx] = V[((size_t)(b * SEQ + s0 + ty + i)) * ld + h * HD + d0 + tx];
    __syncthreads();
#pragma unroll
    for (int i = 0; i < 32; i += 8)
        Vt[((size_t)bh * HD + d0 + ty + i) * SEQ + s0 + tx] = t[tx][ty + i];
}

// ---------------- 256x256 NT GEMM, 8-phase (R18 kernel + ldC) ----------------
template <int OUTF32>
__global__ __launch_bounds__(512, 2)
void gemm256(const bf16* __restrict__ A, const bf16* __restrict__ B,
             void* __restrict__ Cout, int M, int N, int K, int ldC) {
    __shared__ __align__(16) bf16 lds[2][2][2][128 * 64];  // [buf][A/B][unit][.]

    const int nN = N >> 8;
    const int cpx = gridDim.x >> 3;
    const int lin = (blockIdx.x & 7) * cpx + (blockIdx.x >> 3);  // XCD-chunked
    const int m0 = (lin / nN) * 256, n0 = (lin % nN) * 256;

    const int tid = threadIdx.x;
    const int w = tid >> 6, l = tid & 63;
    const int wm = w >> 2, wn = w & 3;
    const int lg = l >> 4, lc = l & 15;
    const int swz = (lc & 7) << 4;
    const int NT = K >> 6;

    f32x4 acc[2][2][4][2] = {};   // [mq][nq][mt][nt]

    auto stage = [&](int tau, int ab, int u) {
        bf16* dst = &lds[tau & 1][ab][u][0];
        const bf16* src = (ab == 0) ? A + (size_t)(m0 + u * 128) * K
                                    : B + (size_t)(n0 + u * 128) * K;
#pragma unroll
        for (int j = 0; j < 2; ++j) {
            int r = w * 16 + j * 8 + (l >> 3);
            int scb = ((l & 7) * 16) ^ ((r & 7) << 4);
            gld16(dst + (w * 16 + j * 8) * 64, src + (size_t)r * K + tau * 64 + (scb >> 1));
        }
    };

    stage(0, 0, 0); stage(0, 0, 1); stage(0, 1, 0); stage(0, 1, 1);
    stage(1, 1, 0); stage(1, 0, 0);
    SBAR();
    asm volatile("s_waitcnt vmcnt(4)" ::: "memory");
    HWBAR();

    for (int t = 0; t < NT; ++t) {
        const char* Ab = (const char*)&lds[t & 1][0][wm][0];
        const char* Bb = (const char*)&lds[t & 1][1][wn >> 1][0];
        const int brow0 = (wn & 1) * 64;
        bf16x8 Af[4][2], Bf[2][2][2];

        // ---- phase 0: (mq0, nq0); stage B1(t+1) ----
#pragma unroll
        for (int mt = 0; mt < 4; ++mt)
#pragma unroll
            for (int ks = 0; ks < 2; ++ks)
                Af[mt][ks] = *(const bf16x8*)(Ab + (mt * 16 + lc) * 128 + ((ks * 64 + lg * 16) ^ swz));
#pragma unroll
        for (int nt = 0; nt < 2; ++nt)
#pragma unroll
            for (int ks = 0; ks < 2; ++ks)
                Bf[0][nt][ks] = *(const bf16x8*)(Bb + (brow0 + nt * 16 + lc) * 128 + ((ks * 64 + lg * 16) ^ swz));
        if (t + 1 < NT) stage(t + 1, 1, 1);
        SBAR(); __builtin_amdgcn_s_barrier();
        asm volatile("s_waitcnt lgkmcnt(0)" ::: "memory"); SBAR();
        __builtin_amdgcn_s_setprio(1);
#pragma unroll
        for (int mt = 0; mt < 4; ++mt)
#pragma unroll
            for (int nt = 0; nt < 2; ++nt)
#pragma unroll
                for (int ks = 0; ks < 2; ++ks)
                    acc[0][0][mt][nt] = __builtin_amdgcn_mfma_f32_16x16x32_bf16(Af[mt][ks], Bf[0][nt][ks], acc[0][0][mt][nt], 0, 0, 0);
        __builtin_amdgcn_s_setprio(0);
        HWBAR();

        // ---- phase 1: (mq0, nq1); stage A1(t+1) ----
#pragma unroll
        for (int nt = 0; nt < 2; ++nt)
#pragma unroll
            for (int ks = 0; ks < 2; ++ks)
                Bf[1][nt][ks] = *(const bf16x8*)(Bb + (brow0 + 32 + nt * 16 + lc) * 128 + ((ks * 64 + lg * 16) ^ swz));
        if (t + 1 < NT) stage(t + 1, 0, 1);
        SBAR(); __builtin_amdgcn_s_barrier();
        asm volatile("s_waitcnt lgkmcnt(0)" ::: "memory"); SBAR();
        __builtin_amdgcn_s_setprio(1);
#pragma unroll
        for (int mt = 0; mt < 4; ++mt)
#pragma unroll
            for (int nt = 0; nt < 2; ++nt)
#pragma unroll
                for (int ks = 0; ks < 2; ++ks)
                    acc[0][1][mt][nt] = __builtin_amdgcn_mfma_f32_16x16x32_bf16(Af[mt][ks], Bf[1][nt][ks], acc[0][1][mt][nt], 0, 0, 0);
        __builtin_amdgcn_s_setprio(0);
        HWBAR();

        // ---- phase 2: (mq1, nq0); stage B0(t+2) ----
#pragma unroll
        for (int mt = 0; mt < 4; ++mt)
#pragma unroll
            for (int ks = 0; ks < 2; ++ks)
                Af[mt][ks] = *(const bf16x8*)(Ab + (64 + mt * 16 + lc) * 128 + ((ks * 64 + lg * 16) ^ swz));
        if (t + 2 < NT) stage(t + 2, 1, 0);
        SBAR(); __builtin_amdgcn_s_barrier();
        asm volatile("s_waitcnt lgkmcnt(0)" ::: "memory"); SBAR();
        __builtin_amdgcn_s_setprio(1);
#pragma unroll
        for (int mt = 0; mt < 4; ++mt)
#pragma unroll
            for (int nt = 0; nt < 2; ++nt)
#pragma unroll
                for (int ks = 0; ks < 2; ++ks)
                    acc[1][0][mt][nt] = __builtin_amdgcn_mfma_f32_16x16x32_bf16(Af[mt][ks], Bf[0][nt][ks], acc[1][0][mt][nt], 0, 0, 0);
        __builtin_amdgcn_s_setprio(0);
        HWBAR();

        // ---- phase 3: (mq1, nq1); stage A0(t+2); boundary vmcnt ----
        if (t + 2 < NT) stage(t + 2, 0, 0);
        SBAR(); __builtin_amdgcn_s_barrier(); SBAR();
        __builtin_amdgcn_s_setprio(1);
#pragma unroll
        for (int mt = 0; mt < 4; ++mt)
#pragma unroll
            for (int nt = 0; nt < 2; ++nt)
#pragma unroll
                for (int ks = 0; ks < 2; ++ks)
                    acc[1][1][mt][nt] = __builtin_amdgcn_mfma_f32_16x16x32_bf16(Af[mt][ks], Bf[1][nt][ks], acc[1][1][mt][nt], 0, 0, 0);
        __builtin_amdgcn_s_setprio(0);
        SBAR();
        if (t + 2 < NT) asm volatile("s_waitcnt vmcnt(4)" ::: "memory");
        else            asm volatile("s_waitcnt vmcnt(0)" ::: "memory");
        __builtin_amdgcn_s_barrier(); SBAR();
    }

#pragma unroll
    for (int mq = 0; mq < 2; ++mq)
#pragma unroll
        for (int nq = 0; nq < 2; ++nq)
#pragma unroll
            for (int mt = 0; mt < 4; ++mt)
#pragma unroll
                for (int nt = 0; nt < 2; ++nt)
#pragma unroll
                    for (int rr = 0; rr < 4; ++rr) {
                        size_t row = (size_t)m0 + wm * 128 + mq * 64 + mt * 16 + lg * 4 + rr;
                        size_t col = (size_t)n0 + wn * 64 + nq * 32 + nt * 16 + lc;
                        float v = acc[mq][nq][mt][nt][rr];
                        if (OUTF32) ((float*)Cout)[row * ldC + col] = v;
                        else        ((bf16*)Cout)[row * ldC + col] = (bf16)v;
                    }
}

// ---------------- 128x256 NT GEMM, 2-phase (R11-exact + ldC) ----------------
template <int OUTF32>
__global__ __launch_bounds__(512, 2)
void gemm128(const bf16* __restrict__ A, const bf16* __restrict__ B,
             void* __restrict__ Cout, int M, int N, int K, int ldC) {
    __shared__ __align__(16) bf16 ldsA[2][128 * 64];
    __shared__ __align__(16) bf16 ldsB[2][2][128 * 64];

    const int nN = N >> 8;
    const int cpx = gridDim.x >> 3;
    const int lin = (blockIdx.x & 7) * cpx + (blockIdx.x >> 3);  // XCD-chunked
    const int m0 = (lin / nN) * 128, n0 = (lin % nN) * 256;

    const int tid = threadIdx.x;
    const int w = tid >> 6, l = tid & 63;
    const int wm = w >> 2, wn = w & 3;
    const int lg = l >> 4, lc = l & 15;
    const int swz = (lc & 7) << 4;
    const int NT = K >> 6;

    f32x4 acc[2][4][2] = {};   // [nq][mt][nt]

    auto stageA = [&](int tau) {
        bf16* dst = &ldsA[tau & 1][0];
#pragma unroll
        for (int j = 0; j < 2; ++j) {
            int r = w * 16 + j * 8 + (l >> 3);
            int scb = ((l & 7) * 16) ^ ((r & 7) << 4);
            gld16(dst + (w * 16 + j * 8) * 64, A + (size_t)(m0 + r) * K + tau * 64 + (scb >> 1));
        }
    };
    auto stageB = [&](int tau, int u) {
        bf16* dst = &ldsB[tau & 1][u][0];
#pragma unroll
        for (int j = 0; j < 2; ++j) {
            int r = w * 16 + j * 8 + (l >> 3);
            int scb = ((l & 7) * 16) ^ ((r & 7) << 4);
            gld16(dst + (w * 16 + j * 8) * 64, B + (size_t)(n0 + u * 128 + r) * K + tau * 64 + (scb >> 1));
        }
    };

    stageA(0); stageB(0, 0); stageB(0, 1); stageA(1);
    SBAR();
    asm volatile("s_waitcnt vmcnt(2)" ::: "memory");
    HWBAR();

    for (int t = 0; t < NT; ++t) {
        const int c = t & 1;
        const char* Ab = (const char*)&ldsA[c][0];
        const char* Bb = (const char*)&ldsB[c][wn >> 1][0];
        const int brow0 = (wn & 1) * 64;
        bf16x8 Af[4][2], Bf[2][2];

#pragma unroll
        for (int mt = 0; mt < 4; ++mt)
#pragma unroll
            for (int ks = 0; ks < 2; ++ks)
                Af[mt][ks] = *(const bf16x8*)(Ab + (wm * 64 + mt * 16 + lc) * 128 + ((ks * 64 + lg * 16) ^ swz));
#pragma unroll
        for (int nt = 0; nt < 2; ++nt)
#pragma unroll
            for (int ks = 0; ks < 2; ++ks)
                Bf[nt][ks] = *(const bf16x8*)(Bb + (brow0 + nt * 16 + lc) * 128 + ((ks * 64 + lg * 16) ^ swz));
        if (t + 1 < NT) stageB(t + 1, 0);
        HWBAR();
        __builtin_amdgcn_s_setprio(1);
#pragma unroll
        for (int mt = 0; mt < 4; ++mt)
#pragma unroll
            for (int nt = 0; nt < 2; ++nt)
#pragma unroll
                for (int ks = 0; ks < 2; ++ks)
                    acc[0][mt][nt] = __builtin_amdgcn_mfma_f32_16x16x32_bf16(Af[mt][ks], Bf[nt][ks], acc[0][mt][nt], 0, 0, 0);
        __builtin_amdgcn_s_setprio(0);
        HWBAR();

#pragma unroll
        for (int nt = 0; nt < 2; ++nt)
#pragma unroll
            for (int ks = 0; ks < 2; ++ks)
                Bf[nt][ks] = *(const bf16x8*)(Bb + (brow0 + 32 + nt * 16 + lc) * 128 + ((ks * 64 + lg * 16) ^ swz));
        if (t + 1 < NT) stageB(t + 1, 1);
        if (t + 2 < NT) stageA(t + 2);
        HWBAR();
        __builtin_amdgcn_s_setprio(1);
#pragma unroll
        for (int mt = 0; mt < 4; ++mt)
#pragma unroll
            for (int nt = 0; nt < 2; ++nt)
#pragma unroll
                for (int ks = 0; ks < 2; ++ks)
                    acc[1][mt][nt] = __builtin_amdgcn_mfma_f32_16x16x32_bf16(Af[mt][ks], Bf[nt][ks], acc[1][mt][nt], 0, 0, 0);
        __builtin_amdgcn_s_setprio(0);
        SBAR();
        if (t + 2 < NT) asm volatile("s_waitcnt vmcnt(2)" ::: "memory");
        else            asm volatile("s_waitcnt vmcnt(0)" ::: "memory");
        HWBAR();
    }

#pragma unroll
    for (int nq = 0; nq < 2; ++nq)
#pragma unroll
        for (int mt = 0; mt < 4; ++mt)
#pragma unroll
            for (int nt = 0; nt < 2; ++nt)
#pragma unroll
                for (int rr = 0; rr < 4; ++rr) {
                    size_t row = (size_t)m0 + wm * 64 + mt * 16 + lg * 4 + rr;
                    size_t col = (size_t)n0 + wn * 64 + nq * 32 + nt * 16 + lc;
                    float v = acc[nq][mt][nt][rr];
                    if (OUTF32) ((float*)Cout)[row * ldC + col] = v;
                    else        ((bf16*)Cout)[row * ldC + col] = (bf16)v;
                }
}

// ---------------- Flash attention (R17-exact) ----------------
__global__ __launch_bounds__(512)
void flash_attn(const bf16* __restrict__ QKV, const bf16* __restrict__ Vt,
                bf16* __restrict__ O) {
    __shared__ __align__(16) bf16 Ks[2][64 * 128];   // [key][d], rows 256B (32 KB)
    __shared__ __align__(16) bf16 Vs[2][128 * 64];   // [d][key], rows 128B (32 KB)
    __shared__ __align__(16) bf16 p_lds[8][16 * 64]; // per-wave P[q][key] (16 KB)

    const int bid = blockIdx.x;                   // 512
    const int xcd = bid & 7, loc = bid >> 3;      // loc 0..63
    const int bh = (xcd << 2) + (loc & 3);        // 4 heads per XCD
    const int jjj = loc >> 2;                     // 0..15
    const int qt = (jjj < 8) ? (15 - jjj) : (jjj - 8);  // complementary pairing
    const int b = bh >> 4, h = bh & 15;

    const int tid = threadIdx.x;
    const int w = tid >> 6, l = tid & 63;         // w 0..7
    const int lg = l >> 4, lc = l & 15;
    const int kswz = (lc & 7) << 4;
    char* pb = (char*)&p_lds[w][0];

    auto stageK = [&](int p, int kb) {
#pragma unroll
        for (int c = 0; c < 2; ++c) {
            int r = c * 32 + w * 4 + (l >> 4);
            int scb = ((l & 15) * 16) ^ ((r & 7) << 4);
            const bf16* g = QKV + ((size_t)(b * SEQ + kb * 64 + r)) * QKV_LD + D_MODEL + h * HD + (scb >> 1);
            gld16(&Ks[p][(c * 32 + w * 4) * 128], g);
        }
    };
    auto stageV = [&](int p, int kb) {
#pragma unroll
        for (int c = 0; c < 2; ++c) {
            int r = c * 64 + w * 8 + (l >> 3);
            int scb = ((l & 7) * 16) ^ ((r & 7) << 4);
            const bf16* g = Vt + ((size_t)bh * HD + r) * SEQ + kb * 64 + (scb >> 1);
            gld16(&Vs[p][(c * 64 + w * 8) * 64], g);
        }
    };

    const int q0 = qt * 128 + w * 16;
    const int kbmax = 2 * qt + 1;                 // last key block index

    const bf16* qp = QKV + ((size_t)(b * SEQ + q0 + lc)) * QKV_LD + h * HD + lg * 8;
    bf16x8 qf[4];
#pragma unroll
    for (int kc = 0; kc < 4; ++kc) qf[kc] = *(const bf16x8*)(qp + kc * 32);

    f32x4 ctx[8] = {};
    float m_s = -INFINITY, l_s = 0.f;

    int cur = 0;
    stageK(cur, 0);
    stageV(cur, 0);

    for (int kb = 0; kb <= kbmax; ++kb) {
        __syncthreads();
        if (kb < kbmax) { stageK(cur ^ 1, kb + 1); stageV(cur ^ 1, kb + 1); }

        const char* kbp = (const char*)&Ks[cur][0];
        f32x4 st[4] = {};
#pragma unroll
        for (int nf = 0; nf < 4; ++nf) {
            int krow = nf * 16 + lc;
#pragma unroll
            for (int kc = 0; kc < 4; ++kc) {
                bf16x8 kf = *(const bf16x8*)(kbp + krow * 256 + ((kc * 64 + lg * 16) ^ kswz));
                st[nf] = __builtin_amdgcn_mfma_f32_16x16x32_bf16(kf, qf[kc], st[nf], 0, 0, 0);
            }
        }

        if (kb >= 2 * qt) {  // diagonal region: mask key > q
            int q = q0 + lc;
#pragma unroll
            for (int nf = 0; nf < 4; ++nf) {
                int key = kb * 64 + nf * 16 + lg * 4;
#pragma unroll
                for (int r = 0; r < 4; ++r)
                    if (key + r > q) st[nf][r] = -INFINITY;
            }
        }

        // row max: in-lane tree + 2 shfl stages
        float m01 = fmaxf(fmaxf(st[0][0], st[0][1]), fmaxf(st[0][2], st[0][3]));
        float m23 = fmaxf(fmaxf(st[1][0], st[1][1]), fmaxf(st[1][2], st[1][3]));
        float m45 = fmaxf(fmaxf(st[2][0], st[2][1]), fmaxf(st[2][2], st[2][3]));
        float m67 = fmaxf(fmaxf(st[3][0], st[3][1]), fmaxf(st[3][2], st[3][3]));
        float mx = fmaxf(fmaxf(m01, m23), fmaxf(m45, m67));
        mx = fmaxf(mx, __shfl_xor(mx, 16));
        mx = fmaxf(mx, __shfl_xor(mx, 32));

        // T13 defer-max: skip rescale while max growth <= 8 (P bounded by e^8)
        bool defer = __all(mx <= m_s + 8.f) && (m_s > -INFINITY);
        float mi;
        if (defer) {
            mi = m_s;
        } else {
            mi = fmaxf(m_s, mx);
            float scv = __expf(m_s - mi);
            float scvr[4];
#pragma unroll
            for (int r = 0; r < 4; ++r) scvr[r] = __shfl(scv, lg * 4 + r);
#pragma unroll
            for (int nd = 0; nd < 8; ++nd)
#pragma unroll
                for (int r = 0; r < 4; ++r) ctx[nd][r] *= scvr[r];
            l_s *= scv;
            m_s = mi;
        }

        float rs = 0.f;
#pragma unroll
        for (int nf = 0; nf < 4; ++nf) {
            float p0 = __expf(st[nf][0] - mi);
            float p1 = __expf(st[nf][1] - mi);
            float p2 = __expf(st[nf][2] - mi);
            float p3 = __expf(st[nf][3] - mi);
            rs += (p0 + p1) + (p2 + p3);
            bf16x4 pv = { (bf16)p0, (bf16)p1, (bf16)p2, (bf16)p3 };
            *(bf16x4*)(pb + lc * 128 + ((nf * 32 + lg * 8) ^ kswz)) = pv;
        }
        rs += __shfl_xor(rs, 16);
        rs += __shfl_xor(rs, 32);
        l_s += rs;

        asm volatile("s_waitcnt lgkmcnt(0)" ::: "memory");
        SBAR();
        bf16x8 pa0 = *(const bf16x8*)(pb + lc * 128 + ((lg * 16) ^ kswz));
        bf16x8 pa1 = *(const bf16x8*)(pb + lc * 128 + ((64 + lg * 16) ^ kswz));

        const char* vb = (const char*)&Vs[cur][0];
#pragma unroll
        for (int nd = 0; nd < 8; ++nd) {
            int vrow = nd * 16 + lc;
#pragma unroll
            for (int k2 = 0; k2 < 2; ++k2) {
                bf16x8 vf = *(const bf16x8*)(vb + vrow * 128 + ((k2 * 64 + lg * 16) ^ kswz));
                ctx[nd] = __builtin_amdgcn_mfma_f32_16x16x32_bf16(k2 ? pa1 : pa0, vf, ctx[nd], 0, 0, 0);
            }
        }
        cur ^= 1;
    }

    float lr[4];
#pragma unroll
    for (int r = 0; r < 4; ++r) lr[r] = 1.f / __shfl(l_s, lg * 4 + r);
#pragma unroll
    for (int nd = 0; nd < 8; ++nd)
#pragma unroll
        for (int r = 0; r < 4; ++r)
            O[((size_t)(b * SEQ + q0 + lg * 4 + r)) * D_MODEL + h * HD + nd * 16 + lc] =
                (bf16)(ctx[nd][r] * lr[r]);
}

// ---------------- launch ----------------
extern "C" void kernel_launch(void* const* d_in, const int* in_sizes, int n_in,
                              void* d_out, int out_size, void* d_ws, size_t ws_size,
                              hipStream_t stream) {
    const float* x  = (const float*)d_in[0];
    const float* Wq = (const float*)d_in[1];
    const float* Wk = (const float*)d_in[2];
    const float* Wv = (const float*)d_in[3];
    const float* Wo = (const float*)d_in[4];

    char* ws = (char*)d_ws;
    bf16* xb   = (bf16*)(ws + 0);            // 16 MB; reused as ctx after QKV GEMM
    bf16* wqkv = (bf16*)(ws + 16777216);     // 24 MB  [6144][2048]
    bf16* wob  = (bf16*)(ws + 41943040);     // 8 MB
    bf16* QKV  = (bf16*)(ws + 50331648);     // 48 MB  [4096][6144]
    bf16* Vtb  = (bf16*)(ws + 100663296);    // 16 MB  [B,H,D,S]
    float* cosd = (float*)(ws + 117440512);
    float* sind = (float*)(ws + 117964800);

    // fused convert: 25165824 elems -> contiguous xb|wqkv|wob
    cvt_all<<<25165824 / 1024, 256, 0, stream>>>(x, Wq, Wk, Wv, Wo, xb);

    rope_tables_k<<<(SEQ * 64) / 256, 256, 0, stream>>>(cosd, sind);

    // QK projection: [4096,2048] x [4096,2048]^T -> QKV cols 0..4095
    // 256x256 tiles: 16x16 = 256 blocks = exactly 1 round
    gemm256<0><<<dim3(256), 512, 0, stream>>>(
        xb, wqkv, QKV, BATCH * SEQ, 2 * D_MODEL, D_MODEL, QKV_LD);

    // V projection: [4096,2048] x [2048,2048]^T -> QKV cols 4096..6143
    // 128x256 tiles: 32x8 = 256 blocks = exactly 1 round
    gemm128<0><<<dim3(256), 512, 0, stream>>>(
        xb, wqkv + (size_t)2 * D_MODEL * D_MODEL, QKV + 2 * D_MODEL,
        BATCH * SEQ, D_MODEL, D_MODEL, QKV_LD);

    const float qscale = 0.08838834764831845f;  // 1/sqrt(128)
    rope_apply2<<<(2 * BATCH * SEQ * 1024) / 256, 256, 0, stream>>>(QKV, cosd, sind, qscale);

    transpose_v<<<dim3(SEQ / 32, HD / 32, BATCH * NH), 256, 0, stream>>>(QKV + 2 * D_MODEL, Vtb, QKV_LD);

    flash_attn<<<dim3(512), 512, 0, stream>>>(QKV, Vtb, xb /*ctx*/);

    // output projection: [4096,2048] x [2048,2048]^T -> d_out (f32)
    gemm128<1><<<dim3(256), 512, 0, stream>>>(
        xb, wob, d_out, BATCH * SEQ, D_MODEL, D_MODEL, D_MODEL);
}

// Round 20
// 251.553 us; speedup vs baseline: 1.1333x; 1.0074x over previous
//
#include <hip/hip_runtime.h>
#include <hip/hip_bf16.h>
#include <cstdint>
#include <cstddef>

typedef __bf16 bf16;
typedef __bf16 bf16x4 __attribute__((ext_vector_type(4)));
typedef __bf16 bf16x8 __attribute__((ext_vector_type(8)));
typedef float f32x4 __attribute__((ext_vector_type(4)));

#define D_MODEL 2048
#define SEQ     2048
#define NH      16
#define HD      128
#define BATCH   2
#define QKV_LD  6144

#define SBAR()  __builtin_amdgcn_sched_barrier(0)
#define HWBAR() do { SBAR(); __builtin_amdgcn_s_barrier(); SBAR(); } while (0)

// ---------------- async global->LDS 16B ----------------
__device__ __forceinline__ void gld16(void* lds, const void* g) {
    __builtin_amdgcn_global_load_lds(
        (const __attribute__((address_space(1))) unsigned int*)g,
        (__attribute__((address_space(3))) unsigned int*)lds,
        16, 0, 0);
}

// ---------------- fused fp32 -> bf16 convert (x, Wq, Wk, Wv, Wo) ----------------
__global__ __launch_bounds__(256) void cvt_all(const float* __restrict__ x,
                                               const float* __restrict__ Wq,
                                               const float* __restrict__ Wk,
                                               const float* __restrict__ Wv,
                                               const float* __restrict__ Wo,
                                               bf16* __restrict__ out) {
    int i = (blockIdx.x * 256 + threadIdx.x) * 4;  // 25165824 total elems
    const float* src;
    int off;
    if (i < 8388608) { src = x; off = i; }
    else {
        int j = i - 8388608;
        int seg = j >> 22;
        src = (seg == 0) ? Wq : (seg == 1) ? Wk : (seg == 2) ? Wv : Wo;
        off = j & 4194303;
    }
    float4 v = *(const float4*)(src + off);
    bf16* o = out + i;
    o[0] = (bf16)v.x; o[1] = (bf16)v.y; o[2] = (bf16)v.z; o[3] = (bf16)v.w;
}

// ---------------- RoPE tables (cos/sin, S x 64) ----------------
__global__ __launch_bounds__(256) void rope_tables_k(float* __restrict__ cosd,
                                                     float* __restrict__ sind) {
    int id = blockIdx.x * 256 + threadIdx.x;  // SEQ*64
    int s = id >> 6, d = id & 63;
    float freq = powf(10000.f, -(float)d * (1.f / 64.f));
    float a = (float)s * freq;
    float sn, c;
    sincosf(a, &sn, &c);
    cosd[id] = c;
    sind[id] = sn;
}

// ---------------- merged RoPE(Q,K) + V transpose, one dispatch ----------------
// bids 0..32767: rope on Q/K regions (2^23 threads, half = Q/K).
// bids 32768..40959: V transpose [B,S,ld] -> [B,H,D,S] (8192 tile blocks).
__global__ __launch_bounds__(256) void rope_tr(bf16* __restrict__ T,
                                               const float* __restrict__ cosd,
                                               const float* __restrict__ sind,
                                               float qscale,
                                               bf16* __restrict__ Vt) {
    __shared__ bf16 t[32][33];
    const int bid = blockIdx.x;
    if (bid < 32768) {
        int id = bid * 256 + threadIdx.x;
        int half = id >> 22;                       // 0 = Q, 1 = K
        int jd = id & 4194303;                     // 2^22 - 1
        int row = jd >> 10;                        // B*S
        int p = jd & 1023;
        int h = p >> 6, d = p & 63;
        int s = row & (SEQ - 1);
        size_t base = (size_t)row * QKV_LD + half * D_MODEL + h * HD + d;
        float scale = half ? 1.0f : qscale;
        float x1 = (float)T[base];
        float x2 = (float)T[base + 64];
        float c = cosd[(s << 6) + d];
        float sn = sind[(s << 6) + d];
        T[base]      = (bf16)((x1 * c - x2 * sn) * scale);
        T[base + 64] = (bf16)((x2 * c + x1 * sn) * scale);
    } else {
        const bf16* V = T + 2 * D_MODEL;           // V region of QKV
        int lin = bid - 32768;
        int s0 = (lin & 63) * 32;
        int d0 = ((lin >> 6) & 3) * 32;
        int bh = lin >> 8;
        int b = bh >> 4, h = bh & 15;
        int tx = threadIdx.x & 31, ty = threadIdx.x >> 5;  // ty 0..7
#pragma unroll
        for (int i = 0; i < 32; i += 8)
            t[ty + i][tx] = V[((size_t)(b * SEQ + s0 + ty + i)) * QKV_LD + h * HD + d0 + tx];
        __syncthreads();
#pragma unroll
        for (int i = 0; i < 32; i += 8)
            Vt[((size_t)bh * HD + d0 + ty + i) * SEQ + s0 + tx] = t[tx][ty + i];
    }
}

// ---------------- 256x256 NT GEMM, 8-phase (R18 kernel + ldC) ----------------
template <int OUTF32>
__global__ __launch_bounds__(512, 2)
void gemm256(const bf16* __restrict__ A, const bf16* __restrict__ B,
             void* __restrict__ Cout, int M, int N, int K, int ldC) {
    __shared__ __align__(16) bf16 lds[2][2][2][128 * 64];  // [buf][A/B][unit][.]

    const int nN = N >> 8;
    const int cpx = gridDim.x >> 3;
    const int lin = (blockIdx.x & 7) * cpx + (blockIdx.x >> 3);  // XCD-chunked
    const int m0 = (lin / nN) * 256, n0 = (lin % nN) * 256;

    const int tid = threadIdx.x;
    const int w = tid >> 6, l = tid & 63;
    const int wm = w >> 2, wn = w & 3;
    const int lg = l >> 4, lc = l & 15;
    const int swz = (lc & 7) << 4;
    const int NT = K >> 6;

    f32x4 acc[2][2][4][2] = {};   // [mq][nq][mt][nt]

    auto stage = [&](int tau, int ab, int u) {
        bf16* dst = &lds[tau & 1][ab][u][0];
        const bf16* src = (ab == 0) ? A + (size_t)(m0 + u * 128) * K
                                    : B + (size_t)(n0 + u * 128) * K;
#pragma unroll
        for (int j = 0; j < 2; ++j) {
            int r = w * 16 + j * 8 + (l >> 3);
            int scb = ((l & 7) * 16) ^ ((r & 7) << 4);
            gld16(dst + (w * 16 + j * 8) * 64, src + (size_t)r * K + tau * 64 + (scb >> 1));
        }
    };

    stage(0, 0, 0); stage(0, 0, 1); stage(0, 1, 0); stage(0, 1, 1);
    stage(1, 1, 0); stage(1, 0, 0);
    SBAR();
    asm volatile("s_waitcnt vmcnt(4)" ::: "memory");
    HWBAR();

    for (int t = 0; t < NT; ++t) {
        const char* Ab = (const char*)&lds[t & 1][0][wm][0];
        const char* Bb = (const char*)&lds[t & 1][1][wn >> 1][0];
        const int brow0 = (wn & 1) * 64;
        bf16x8 Af[4][2], Bf[2][2][2];

        // ---- phase 0: (mq0, nq0); stage B1(t+1) ----
#pragma unroll
        for (int mt = 0; mt < 4; ++mt)
#pragma unroll
            for (int ks = 0; ks < 2; ++ks)
                Af[mt][ks] = *(const bf16x8*)(Ab + (mt * 16 + lc) * 128 + ((ks * 64 + lg * 16) ^ swz));
#pragma unroll
        for (int nt = 0; nt < 2; ++nt)
#pragma unroll
            for (int ks = 0; ks < 2; ++ks)
                Bf[0][nt][ks] = *(const bf16x8*)(Bb + (brow0 + nt * 16 + lc) * 128 + ((ks * 64 + lg * 16) ^ swz));
        if (t + 1 < NT) stage(t + 1, 1, 1);
        SBAR(); __builtin_amdgcn_s_barrier();
        asm volatile("s_waitcnt lgkmcnt(0)" ::: "memory"); SBAR();
        __builtin_amdgcn_s_setprio(1);
#pragma unroll
        for (int mt = 0; mt < 4; ++mt)
#pragma unroll
            for (int nt = 0; nt < 2; ++nt)
#pragma unroll
                for (int ks = 0; ks < 2; ++ks)
                    acc[0][0][mt][nt] = __builtin_amdgcn_mfma_f32_16x16x32_bf16(Af[mt][ks], Bf[0][nt][ks], acc[0][0][mt][nt], 0, 0, 0);
        __builtin_amdgcn_s_setprio(0);
        HWBAR();

        // ---- phase 1: (mq0, nq1); stage A1(t+1) ----
#pragma unroll
        for (int nt = 0; nt < 2; ++nt)
#pragma unroll
            for (int ks = 0; ks < 2; ++ks)
                Bf[1][nt][ks] = *(const bf16x8*)(Bb + (brow0 + 32 + nt * 16 + lc) * 128 + ((ks * 64 + lg * 16) ^ swz));
        if (t + 1 < NT) stage(t + 1, 0, 1);
        SBAR(); __builtin_amdgcn_s_barrier();
        asm volatile("s_waitcnt lgkmcnt(0)" ::: "memory"); SBAR();
        __builtin_amdgcn_s_setprio(1);
#pragma unroll
        for (int mt = 0; mt < 4; ++mt)
#pragma unroll
            for (int nt = 0; nt < 2; ++nt)
#pragma unroll
                for (int ks = 0; ks < 2; ++ks)
                    acc[0][1][mt][nt] = __builtin_amdgcn_mfma_f32_16x16x32_bf16(Af[mt][ks], Bf[1][nt][ks], acc[0][1][mt][nt], 0, 0, 0);
        __builtin_amdgcn_s_setprio(0);
        HWBAR();

        // ---- phase 2: (mq1, nq0); stage B0(t+2) ----
#pragma unroll
        for (int mt = 0; mt < 4; ++mt)
#pragma unroll
            for (int ks = 0; ks < 2; ++ks)
                Af[mt][ks] = *(const bf16x8*)(Ab + (64 + mt * 16 + lc) * 128 + ((ks * 64 + lg * 16) ^ swz));
        if (t + 2 < NT) stage(t + 2, 1, 0);
        SBAR(); __builtin_amdgcn_s_barrier();
        asm volatile("s_waitcnt lgkmcnt(0)" ::: "memory"); SBAR();
        __builtin_amdgcn_s_setprio(1);
#pragma unroll
        for (int mt = 0; mt < 4; ++mt)
#pragma unroll
            for (int nt = 0; nt < 2; ++nt)
#pragma unroll
                for (int ks = 0; ks < 2; ++ks)
                    acc[1][0][mt][nt] = __builtin_amdgcn_mfma_f32_16x16x32_bf16(Af[mt][ks], Bf[0][nt][ks], acc[1][0][mt][nt], 0, 0, 0);
        __builtin_amdgcn_s_setprio(0);
        HWBAR();

        // ---- phase 3: (mq1, nq1); stage A0(t+2); boundary vmcnt ----
        if (t + 2 < NT) stage(t + 2, 0, 0);
        SBAR(); __builtin_amdgcn_s_barrier(); SBAR();
        __builtin_amdgcn_s_setprio(1);
#pragma unroll
        for (int mt = 0; mt < 4; ++mt)
#pragma unroll
            for (int nt = 0; nt < 2; ++nt)
#pragma unroll
                for (int ks = 0; ks < 2; ++ks)
                    acc[1][1][mt][nt] = __builtin_amdgcn_mfma_f32_16x16x32_bf16(Af[mt][ks], Bf[1][nt][ks], acc[1][1][mt][nt], 0, 0, 0);
        __builtin_amdgcn_s_setprio(0);
        SBAR();
        if (t + 2 < NT) asm volatile("s_waitcnt vmcnt(4)" ::: "memory");
        else            asm volatile("s_waitcnt vmcnt(0)" ::: "memory");
        __builtin_amdgcn_s_barrier(); SBAR();
    }

#pragma unroll
    for (int mq = 0; mq < 2; ++mq)
#pragma unroll
        for (int nq = 0; nq < 2; ++nq)
#pragma unroll
            for (int mt = 0; mt < 4; ++mt)
#pragma unroll
                for (int nt = 0; nt < 2; ++nt)
#pragma unroll
                    for (int rr = 0; rr < 4; ++rr) {
                        size_t row = (size_t)m0 + wm * 128 + mq * 64 + mt * 16 + lg * 4 + rr;
                        size_t col = (size_t)n0 + wn * 64 + nq * 32 + nt * 16 + lc;
                        float v = acc[mq][nq][mt][nt][rr];
                        if (OUTF32) ((float*)Cout)[row * ldC + col] = v;
                        else        ((bf16*)Cout)[row * ldC + col] = (bf16)v;
                    }
}

// ---------------- 128x256 NT GEMM, 2-phase (R11-exact + ldC) ----------------
template <int OUTF32>
__global__ __launch_bounds__(512, 2)
void gemm128(const bf16* __restrict__ A, const bf16* __restrict__ B,
             void* __restrict__ Cout, int M, int N, int K, int ldC) {
    __shared__ __align__(16) bf16 ldsA[2][128 * 64];
    __shared__ __align__(16) bf16 ldsB[2][2][128 * 64];

    const int nN = N >> 8;
    const int cpx = gridDim.x >> 3;
    const int lin = (blockIdx.x & 7) * cpx + (blockIdx.x >> 3);  // XCD-chunked
    const int m0 = (lin / nN) * 128, n0 = (lin % nN) * 256;

    const int tid = threadIdx.x;
    const int w = tid >> 6, l = tid & 63;
    const int wm = w >> 2, wn = w & 3;
    const int lg = l >> 4, lc = l & 15;
    const int swz = (lc & 7) << 4;
    const int NT = K >> 6;

    f32x4 acc[2][4][2] = {};   // [nq][mt][nt]

    auto stageA = [&](int tau) {
        bf16* dst = &ldsA[tau & 1][0];
#pragma unroll
        for (int j = 0; j < 2; ++j) {
            int r = w * 16 + j * 8 + (l >> 3);
            int scb = ((l & 7) * 16) ^ ((r & 7) << 4);
            gld16(dst + (w * 16 + j * 8) * 64, A + (size_t)(m0 + r) * K + tau * 64 + (scb >> 1));
        }
    };
    auto stageB = [&](int tau, int u) {
        bf16* dst = &ldsB[tau & 1][u][0];
#pragma unroll
        for (int j = 0; j < 2; ++j) {
            int r = w * 16 + j * 8 + (l >> 3);
            int scb = ((l & 7) * 16) ^ ((r & 7) << 4);
            gld16(dst + (w * 16 + j * 8) * 64, B + (size_t)(n0 + u * 128 + r) * K + tau * 64 + (scb >> 1));
        }
    };

    stageA(0); stageB(0, 0); stageB(0, 1); stageA(1);
    SBAR();
    asm volatile("s_waitcnt vmcnt(2)" ::: "memory");
    HWBAR();

    for (int t = 0; t < NT; ++t) {
        const int c = t & 1;
        const char* Ab = (const char*)&ldsA[c][0];
        const char* Bb = (const char*)&ldsB[c][wn >> 1][0];
        const int brow0 = (wn & 1) * 64;
        bf16x8 Af[4][2], Bf[2][2];

#pragma unroll
        for (int mt = 0; mt < 4; ++mt)
#pragma unroll
            for (int ks = 0; ks < 2; ++ks)
                Af[mt][ks] = *(const bf16x8*)(Ab + (wm * 64 + mt * 16 + lc) * 128 + ((ks * 64 + lg * 16) ^ swz));
#pragma unroll
        for (int nt = 0; nt < 2; ++nt)
#pragma unroll
            for (int ks = 0; ks < 2; ++ks)
                Bf[nt][ks] = *(const bf16x8*)(Bb + (brow0 + nt * 16 + lc) * 128 + ((ks * 64 + lg * 16) ^ swz));
        if (t + 1 < NT) stageB(t + 1, 0);
        HWBAR();
        __builtin_amdgcn_s_setprio(1);
#pragma unroll
        for (int mt = 0; mt < 4; ++mt)
#pragma unroll
            for (int nt = 0; nt < 2; ++nt)
#pragma unroll
                for (int ks = 0; ks < 2; ++ks)
                    acc[0][mt][nt] = __builtin_amdgcn_mfma_f32_16x16x32_bf16(Af[mt][ks], Bf[nt][ks], acc[0][mt][nt], 0, 0, 0);
        __builtin_amdgcn_s_setprio(0);
        HWBAR();

#pragma unroll
        for (int nt = 0; nt < 2; ++nt)
#pragma unroll
            for (int ks = 0; ks < 2; ++ks)
                Bf[nt][ks] = *(const bf16x8*)(Bb + (brow0 + 32 + nt * 16 + lc) * 128 + ((ks * 64 + lg * 16) ^ swz));
        if (t + 1 < NT) stageB(t + 1, 1);
        if (t + 2 < NT) stageA(t + 2);
        HWBAR();
        __builtin_amdgcn_s_setprio(1);
#pragma unroll
        for (int mt = 0; mt < 4; ++mt)
#pragma unroll
            for (int nt = 0; nt < 2; ++nt)
#pragma unroll
                for (int ks = 0; ks < 2; ++ks)
                    acc[1][mt][nt] = __builtin_amdgcn_mfma_f32_16x16x32_bf16(Af[mt][ks], Bf[nt][ks], acc[1][mt][nt], 0, 0, 0);
        __builtin_amdgcn_s_setprio(0);
        SBAR();
        if (t + 2 < NT) asm volatile("s_waitcnt vmcnt(2)" ::: "memory");
        else            asm volatile("s_waitcnt vmcnt(0)" ::: "memory");
        HWBAR();
    }

#pragma unroll
    for (int nq = 0; nq < 2; ++nq)
#pragma unroll
        for (int mt = 0; mt < 4; ++mt)
#pragma unroll
            for (int nt = 0; nt < 2; ++nt)
#pragma unroll
                for (int rr = 0; rr < 4; ++rr) {
                    size_t row = (size_t)m0 + wm * 64 + mt * 16 + lg * 4 + rr;
                    size_t col = (size_t)n0 + wn * 64 + nq * 32 + nt * 16 + lc;
                    float v = acc[nq][mt][nt][rr];
                    if (OUTF32) ((float*)Cout)[row * ldC + col] = v;
                    else        ((bf16*)Cout)[row * ldC + col] = (bf16)v;
                }
}

// ---------------- Flash attention (R17-exact) ----------------
__global__ __launch_bounds__(512)
void flash_attn(const bf16* __restrict__ QKV, const bf16* __restrict__ Vt,
                bf16* __restrict__ O) {
    __shared__ __align__(16) bf16 Ks[2][64 * 128];   // [key][d], rows 256B (32 KB)
    __shared__ __align__(16) bf16 Vs[2][128 * 64];   // [d][key], rows 128B (32 KB)
    __shared__ __align__(16) bf16 p_lds[8][16 * 64]; // per-wave P[q][key] (16 KB)

    const int bid = blockIdx.x;                   // 512
    const int xcd = bid & 7, loc = bid >> 3;      // loc 0..63
    const int bh = (xcd << 2) + (loc & 3);        // 4 heads per XCD
    const int jjj = loc >> 2;                     // 0..15
    const int qt = (jjj < 8) ? (15 - jjj) : (jjj - 8);  // complementary pairing
    const int b = bh >> 4, h = bh & 15;

    const int tid = threadIdx.x;
    const int w = tid >> 6, l = tid & 63;         // w 0..7
    const int lg = l >> 4, lc = l & 15;
    const int kswz = (lc & 7) << 4;
    char* pb = (char*)&p_lds[w][0];

    auto stageK = [&](int p, int kb) {
#pragma unroll
        for (int c = 0; c < 2; ++c) {
            int r = c * 32 + w * 4 + (l >> 4);
            int scb = ((l & 15) * 16) ^ ((r & 7) << 4);
            const bf16* g = QKV + ((size_t)(b * SEQ + kb * 64 + r)) * QKV_LD + D_MODEL + h * HD + (scb >> 1);
            gld16(&Ks[p][(c * 32 + w * 4) * 128], g);
        }
    };
    auto stageV = [&](int p, int kb) {
#pragma unroll
        for (int c = 0; c < 2; ++c) {
            int r = c * 64 + w * 8 + (l >> 3);
            int scb = ((l & 7) * 16) ^ ((r & 7) << 4);
            const bf16* g = Vt + ((size_t)bh * HD + r) * SEQ + kb * 64 + (scb >> 1);
            gld16(&Vs[p][(c * 64 + w * 8) * 64], g);
        }
    };

    const int q0 = qt * 128 + w * 16;
    const int kbmax = 2 * qt + 1;                 // last key block index

    const bf16* qp = QKV + ((size_t)(b * SEQ + q0 + lc)) * QKV_LD + h * HD + lg * 8;
    bf16x8 qf[4];
#pragma unroll
    for (int kc = 0; kc < 4; ++kc) qf[kc] = *(const bf16x8*)(qp + kc * 32);

    f32x4 ctx[8] = {};
    float m_s = -INFINITY, l_s = 0.f;

    int cur = 0;
    stageK(cur, 0);
    stageV(cur, 0);

    for (int kb = 0; kb <= kbmax; ++kb) {
        __syncthreads();
        if (kb < kbmax) { stageK(cur ^ 1, kb + 1); stageV(cur ^ 1, kb + 1); }

        const char* kbp = (const char*)&Ks[cur][0];
        f32x4 st[4] = {};
#pragma unroll
        for (int nf = 0; nf < 4; ++nf) {
            int krow = nf * 16 + lc;
#pragma unroll
            for (int kc = 0; kc < 4; ++kc) {
                bf16x8 kf = *(const bf16x8*)(kbp + krow * 256 + ((kc * 64 + lg * 16) ^ kswz));
                st[nf] = __builtin_amdgcn_mfma_f32_16x16x32_bf16(kf, qf[kc], st[nf], 0, 0, 0);
            }
        }

        if (kb >= 2 * qt) {  // diagonal region: mask key > q
            int q = q0 + lc;
#pragma unroll
            for (int nf = 0; nf < 4; ++nf) {
                int key = kb * 64 + nf * 16 + lg * 4;
#pragma unroll
                for (int r = 0; r < 4; ++r)
                    if (key + r > q) st[nf][r] = -INFINITY;
            }
        }

        // row max: in-lane tree + 2 shfl stages
        float m01 = fmaxf(fmaxf(st[0][0], st[0][1]), fmaxf(st[0][2], st[0][3]));
        float m23 = fmaxf(fmaxf(st[1][0], st[1][1]), fmaxf(st[1][2], st[1][3]));
        float m45 = fmaxf(fmaxf(st[2][0], st[2][1]), fmaxf(st[2][2], st[2][3]));
        float m67 = fmaxf(fmaxf(st[3][0], st[3][1]), fmaxf(st[3][2], st[3][3]));
        float mx = fmaxf(fmaxf(m01, m23), fmaxf(m45, m67));
        mx = fmaxf(mx, __shfl_xor(mx, 16));
        mx = fmaxf(mx, __shfl_xor(mx, 32));

        // T13 defer-max: skip rescale while max growth <= 8 (P bounded by e^8)
        bool defer = __all(mx <= m_s + 8.f) && (m_s > -INFINITY);
        float mi;
        if (defer) {
            mi = m_s;
        } else {
            mi = fmaxf(m_s, mx);
            float scv = __expf(m_s - mi);
            float scvr[4];
#pragma unroll
            for (int r = 0; r < 4; ++r) scvr[r] = __shfl(scv, lg * 4 + r);
#pragma unroll
            for (int nd = 0; nd < 8; ++nd)
#pragma unroll
                for (int r = 0; r < 4; ++r) ctx[nd][r] *= scvr[r];
            l_s *= scv;
            m_s = mi;
        }

        float rs = 0.f;
#pragma unroll
        for (int nf = 0; nf < 4; ++nf) {
            float p0 = __expf(st[nf][0] - mi);
            float p1 = __expf(st[nf][1] - mi);
            float p2 = __expf(st[nf][2] - mi);
            float p3 = __expf(st[nf][3] - mi);
            rs += (p0 + p1) + (p2 + p3);
            bf16x4 pv = { (bf16)p0, (bf16)p1, (bf16)p2, (bf16)p3 };
            *(bf16x4*)(pb + lc * 128 + ((nf * 32 + lg * 8) ^ kswz)) = pv;
        }
        rs += __shfl_xor(rs, 16);
        rs += __shfl_xor(rs, 32);
        l_s += rs;

        asm volatile("s_waitcnt lgkmcnt(0)" ::: "memory");
        SBAR();
        bf16x8 pa0 = *(const bf16x8*)(pb + lc * 128 + ((lg * 16) ^ kswz));
        bf16x8 pa1 = *(const bf16x8*)(pb + lc * 128 + ((64 + lg * 16) ^ kswz));

        const char* vb = (const char*)&Vs[cur][0];
#pragma unroll
        for (int nd = 0; nd < 8; ++nd) {
            int vrow = nd * 16 + lc;
#pragma unroll
            for (int k2 = 0; k2 < 2; ++k2) {
                bf16x8 vf = *(const bf16x8*)(vb + vrow * 128 + ((k2 * 64 + lg * 16) ^ kswz));
                ctx[nd] = __builtin_amdgcn_mfma_f32_16x16x32_bf16(k2 ? pa1 : pa0, vf, ctx[nd], 0, 0, 0);
            }
        }
        cur ^= 1;
    }

    float lr[4];
#pragma unroll
    for (int r = 0; r < 4; ++r) lr[r] = 1.f / __shfl(l_s, lg * 4 + r);
#pragma unroll
    for (int nd = 0; nd < 8; ++nd)
#pragma unroll
        for (int r = 0; r < 4; ++r)
            O[((size_t)(b * SEQ + q0 + lg * 4 + r)) * D_MODEL + h * HD + nd * 16 + lc] =
                (bf16)(ctx[nd][r] * lr[r]);
}

// ---------------- launch ----------------
extern "C" void kernel_launch(void* const* d_in, const int* in_sizes, int n_in,
                              void* d_out, int out_size, void* d_ws, size_t ws_size,
                              hipStream_t stream) {
    const float* x  = (const float*)d_in[0];
    const float* Wq = (const float*)d_in[1];
    const float* Wk = (const float*)d_in[2];
    const float* Wv = (const float*)d_in[3];
    const float* Wo = (const float*)d_in[4];

    char* ws = (char*)d_ws;
    bf16* xb   = (bf16*)(ws + 0);            // 16 MB; reused as ctx after QKV GEMM
    bf16* wqkv = (bf16*)(ws + 16777216);     // 24 MB  [6144][2048]
    bf16* wob  = (bf16*)(ws + 41943040);     // 8 MB
    bf16* QKV  = (bf16*)(ws + 50331648);     // 48 MB  [4096][6144]
    bf16* Vtb  = (bf16*)(ws + 100663296);    // 16 MB  [B,H,D,S]
    float* cosd = (float*)(ws + 117440512);
    float* sind = (float*)(ws + 117964800);

    // fused convert: 25165824 elems -> contiguous xb|wqkv|wob
    cvt_all<<<25165824 / 1024, 256, 0, stream>>>(x, Wq, Wk, Wv, Wo, xb);

    rope_tables_k<<<(SEQ * 64) / 256, 256, 0, stream>>>(cosd, sind);

    // QK projection: [4096,2048] x [4096,2048]^T -> QKV cols 0..4095
    // 256x256 tiles: 16x16 = 256 blocks = exactly 1 round
    gemm256<0><<<dim3(256), 512, 0, stream>>>(
        xb, wqkv, QKV, BATCH * SEQ, 2 * D_MODEL, D_MODEL, QKV_LD);

    // V projection: [4096,2048] x [2048,2048]^T -> QKV cols 4096..6143
    // 128x256 tiles: 32x8 = 256 blocks = exactly 1 round
    gemm128<0><<<dim3(256), 512, 0, stream>>>(
        xb, wqkv + (size_t)2 * D_MODEL * D_MODEL, QKV + 2 * D_MODEL,
        BATCH * SEQ, D_MODEL, D_MODEL, QKV_LD);

    const float qscale = 0.08838834764831845f;  // 1/sqrt(128)
    // merged RoPE(Q,K) + V transpose: 32768 rope blocks + 8192 transpose blocks
    rope_tr<<<dim3(40960), 256, 0, stream>>>(QKV, cosd, sind, qscale, Vtb);

    flash_attn<<<dim3(512), 512, 0, stream>>>(QKV, Vtb, xb /*ctx*/);

    // output projection: [4096,2048] x [2048,2048]^T -> d_out (f32)
    gemm128<1><<<dim3(256), 512, 0, stream>>>(
        xb, wob, d_out, BATCH * SEQ, D_MODEL, D_MODEL, D_MODEL);
}